// Round 4
// baseline (834.383 us; speedup 1.0000x reference)
//
#include <hip/hip_runtime.h>

typedef float f32x4 __attribute__((ext_vector_type(4)));
typedef __bf16 bf16x8 __attribute__((ext_vector_type(8)));
typedef unsigned short ushort_t;

#define DEV_INLINE __device__ __forceinline__

constexpr int B_N  = 2;
constexpr int C3_N = 128;
constexpr int C2_N = 96;
constexpr int DZ_N = 32;
constexpr int H_N  = 24;
constexpr int W_N  = 24;
constexpr int K_N  = 8;
constexpr int E_N  = 256;
constexpr int HW_N = 576;

DEV_INLINE unsigned short f2bf(float x) {
  union { float f; unsigned u; } v; v.f = x;
  unsigned r = v.u + 0x7FFFu + ((v.u >> 16) & 1u);
  return (unsigned short)(r >> 16);
}

// ---------------------------------------------------------------------------
// Topo kernel A: partial 3x3 conv (C2->64), split over 4 c-chunks of 24.
// ---------------------------------------------------------------------------
__global__ __launch_bounds__(384) void topo_conv1(
    const float* __restrict__ F2, const float* __restrict__ W1,
    float* __restrict__ Hp) {
  const int bid = blockIdx.x;
  const int cc = bid & 3;
  const int tg = (bid >> 2) & 3;
  const int bk = bid >> 4;           // 0..15 = b*8 + k
  const int b = bk >> 3, k = bk & 7;
  const int tid = threadIdx.x;
  const int y = tid >> 4;            // 0..23
  const int tq = tid & 15;           // 0..15

  __shared__ float simg[8][26][28];
  __shared__ float sw[16 * 97];

  float acc[24];
#pragma unroll
  for (int i = 0; i < 24; i++) acc[i] = 0.f;

  float* simgf = &simg[0][0][0];
  for (int i = tid; i < 8 * 26 * 28; i += 384) simgf[i] = 0.f;
  __syncthreads();

  for (int ch = 0; ch < 3; ch++) {
    if (ch) __syncthreads();
    const int c0 = cc * 24 + ch * 8;
    for (int i = tid; i < 8 * 24 * 24; i += 384) {
      int c = i / 576, p = i - c * 576;
      int yy = p / 24, xx = p - yy * 24;
      simg[c][yy + 1][xx + 1] =
          F2[(((b * C2_N + c0 + c) * H_N + yy) * W_N + xx) * K_N + k];
    }
    for (int i = tid; i < 16 * 72; i += 384) {
      int t2 = i / 72, rest = i - t2 * 72;
      int c = rest / 9, q = rest - c * 9;
      sw[t2 * 97 + c * 12 + q] =
          W1[(tg * 16 + t2) * (C2_N * 9) + (c0 + c) * 9 + q];
    }
    __syncthreads();
#pragma unroll 1
    for (int c = 0; c < 8; c++) {
      float w[9];
#pragma unroll
      for (int q = 0; q < 9; q++) w[q] = sw[tq * 97 + c * 12 + q];
#pragma unroll
      for (int dy = 0; dy < 3; dy++) {
        float r[26];
#pragma unroll
        for (int xx = 0; xx < 26; xx++) r[xx] = simg[c][y + dy][xx];
#pragma unroll
        for (int dx = 0; dx < 3; dx++) {
          float wv = w[dy * 3 + dx];
#pragma unroll
          for (int xx = 0; xx < 24; xx++)
            acc[xx] = fmaf(wv, r[xx + dx], acc[xx]);
        }
      }
    }
  }
  const int t = tg * 16 + tq;
  float* dst = &Hp[((cc * 16 + bk) * 64 + t) * HW_N + y * 24];
#pragma unroll
  for (int xx = 0; xx < 24; xx++) dst[xx] = acc[xx];
}

// ---------------------------------------------------------------------------
// Topo kernel B: sum partials, bn+relu, 1x1 conv, neighbor sum.
// ---------------------------------------------------------------------------
__global__ __launch_bounds__(576) void topo_final(
    const float* __restrict__ Hp, const float* __restrict__ bn_g,
    const float* __restrict__ bn_b, const float* __restrict__ W2,
    const float* __restrict__ b2, float* __restrict__ topo) {
  const int bk = blockIdx.x;
  const int p = threadIdx.x;
  __shared__ float pp[26][28];
  float* ppf = &pp[0][0];
  for (int i = p; i < 26 * 28; i += 576) ppf[i] = 0.f;

  const float inv = rsqrtf(1.0f + 1e-5f);
  float acc = b2[0];
  for (int t = 0; t < 64; t++) {
    float v = 0.f;
#pragma unroll
    for (int c4 = 0; c4 < 4; c4++)
      v += Hp[((c4 * 16 + bk) * 64 + t) * HW_N + p];
    float hcv = fmaxf(fmaf(bn_g[t] * inv, v, bn_b[t]), 0.f);
    acc = fmaf(W2[t], hcv, acc);
  }
  __syncthreads();
  pp[p / 24 + 1][p % 24 + 1] = acc;
  __syncthreads();
  const int yy = p / 24 + 1, xx = p % 24 + 1;
  float s = pp[yy-1][xx-1] + pp[yy-1][xx] + pp[yy-1][xx+1]
          + pp[yy][xx-1]                  + pp[yy][xx+1]
          + pp[yy+1][xx-1] + pp[yy+1][xx] + pp[yy+1][xx+1];
  topo[bk * HW_N + p] = acc + 0.5f * s;
}

// ---------------------------------------------------------------------------
// Projection GEMM (fp32 vector), now templated on COLS with col-split grid.y.
// ---------------------------------------------------------------------------
template <int CIN, int COLS>
__global__ __launch_bounds__(256) void proj_gemm(
    const float* __restrict__ src, const float* __restrict__ Wm,
    float* __restrict__ outp, int outer, int bStride, int oStride,
    int pStride, int cStride) {
  __shared__ float sA[16][64];
  __shared__ float sW[16][COLS];
  __shared__ int sRB[64];
  const int tid = threadIdx.x;
  const int cb = blockIdx.y * COLS;
  if (tid < 64) {
    int rr = blockIdx.x * 64 + tid;
    int bb = rr / (outer * HW_N);
    int rem = rr - bb * outer * HW_N;
    int o = rem / HW_N;
    int p = rem - o * HW_N;
    sRB[tid] = bb * bStride + o * oStride + p * pStride;
  }
  __syncthreads();
  constexpr int NJ = COLS / 32;
  float accv[8][NJ];
#pragma unroll
  for (int i = 0; i < 8; i++)
#pragma unroll
    for (int j = 0; j < NJ; j++) accv[i][j] = 0.f;
  const int r0 = (tid >> 5) * 8;
  const int c0 = tid & 31;
  for (int k0 = 0; k0 < CIN; k0 += 16) {
    if (k0) __syncthreads();
#pragma unroll
    for (int i = 0; i < 4; i++) {
      int idx = i * 256 + tid;
      int kk = idx >> 6, r = idx & 63;
      sA[kk][r] = src[sRB[r] + (k0 + kk) * cStride];
    }
#pragma unroll
    for (int i = 0; i < 16 * COLS / 256; i++) {
      int idx = i * 256 + tid;
      int kk = idx / COLS, ccc = idx % COLS;
      sW[kk][ccc] = Wm[(k0 + kk) * E_N + cb + ccc];
    }
    __syncthreads();
#pragma unroll 1
    for (int kk = 0; kk < 16; kk++) {
      float4 a0 = *(const float4*)&sA[kk][r0];
      float4 a1 = *(const float4*)&sA[kk][r0 + 4];
      float a[8] = {a0.x, a0.y, a0.z, a0.w, a1.x, a1.y, a1.z, a1.w};
#pragma unroll
      for (int j = 0; j < NJ; j++) {
        float wv = sW[kk][c0 + 32 * j];
#pragma unroll
        for (int i = 0; i < 8; i++) accv[i][j] = fmaf(a[i], wv, accv[i][j]);
      }
    }
  }
  const int rowG = blockIdx.x * 64;
#pragma unroll
  for (int i = 0; i < 8; i++)
#pragma unroll
    for (int j = 0; j < NJ; j++)
      outp[(rowG + r0 + i) * E_N + cb + c0 + 32 * j] = accv[i][j];
}

// ---------------------------------------------------------------------------
// LayerNorm over E=256, fp32 in -> bf16 out (row-major). One wave per row.
// ---------------------------------------------------------------------------
__global__ __launch_bounds__(256) void ln_bf16(
    const float* __restrict__ src, const float* __restrict__ g,
    const float* __restrict__ bb, ushort_t* __restrict__ dst) {
  const int w = threadIdx.x >> 6, lane = threadIdx.x & 63;
  const int row = blockIdx.x * 4 + w;
  const float4 x = *(const float4*)&src[row * E_N + lane * 4];
  float s = x.x + x.y + x.z + x.w;
#pragma unroll
  for (int off = 32; off; off >>= 1) s += __shfl_xor(s, off);
  const float mean = s * (1.f / 256.f);
  float4 d = {x.x - mean, x.y - mean, x.z - mean, x.w - mean};
  float v = d.x * d.x + d.y * d.y + d.z * d.z + d.w * d.w;
#pragma unroll
  for (int off = 32; off; off >>= 1) v += __shfl_xor(v, off);
  const float rstd = rsqrtf(v * (1.f / 256.f) + 1e-5f);
  const float4 gv = *(const float4*)&g[lane * 4];
  const float4 bv = *(const float4*)&bb[lane * 4];
  ushort4 o;
  o.x = f2bf(fmaf(d.x * rstd, gv.x, bv.x));
  o.y = f2bf(fmaf(d.y * rstd, gv.y, bv.y));
  o.z = f2bf(fmaf(d.z * rstd, gv.z, bv.z));
  o.w = f2bf(fmaf(d.w * rstd, gv.w, bv.w));
  *(ushort4*)&dst[row * E_N + lane * 4] = o;
}

// ---------------------------------------------------------------------------
// ln_k_pack: LayerNorm K rows AND scatter into per-(bk,h,pc) packed chunk
// layout [m][d] (16B groups, plain order). One wave per row.
// ---------------------------------------------------------------------------
__global__ __launch_bounds__(256) void ln_k_pack(
    const float* __restrict__ src, const float* __restrict__ g,
    const float* __restrict__ bb, ushort_t* __restrict__ Kpk) {
  const int w = threadIdx.x >> 6, lane = threadIdx.x & 63;
  const int row = blockIdx.x * 4 + w;
  const float4 x = *(const float4*)&src[row * E_N + lane * 4];
  float s = x.x + x.y + x.z + x.w;
#pragma unroll
  for (int off = 32; off; off >>= 1) s += __shfl_xor(s, off);
  const float mean = s * (1.f / 256.f);
  float4 d = {x.x - mean, x.y - mean, x.z - mean, x.w - mean};
  float v = d.x * d.x + d.y * d.y + d.z * d.z + d.w * d.w;
#pragma unroll
  for (int off = 32; off; off >>= 1) v += __shfl_xor(v, off);
  const float rstd = rsqrtf(v * (1.f / 256.f) + 1e-5f);
  const float4 gv = *(const float4*)&g[lane * 4];
  const float4 bv = *(const float4*)&bb[lane * 4];
  ushort4 o;
  o.x = f2bf(fmaf(d.x * rstd, gv.x, bv.x));
  o.y = f2bf(fmaf(d.y * rstd, gv.y, bv.y));
  o.z = f2bf(fmaf(d.z * rstd, gv.z, bv.z));
  o.w = f2bf(fmaf(d.w * rstd, gv.w, bv.w));
  const int bk = row / HW_N;
  const int p = row - bk * HW_N;
  const int pc = p >> 6, m = p & 63;
  const int h = lane >> 4;
  const int dcol = (lane * 4) & 63;
  ushort_t* dst = &Kpk[(((bk * 4 + h) * 9 + pc) * 4096) + m * 64 + dcol];
  *(ushort4*)dst = o;
}

// ---------------------------------------------------------------------------
// pack_vt: Vbf rows -> transposed per-(bk,h,pc) 8KB chunks [d][m'] where the
// key dim is PERMUTED: m' = (m&15)*4 + (m>>4). This makes the attn P-store
// contiguous (b64) while keeping A-frag reads b128. PV = sum over keys, so a
// consistent permutation of P-columns and V-rows is exact.
// ---------------------------------------------------------------------------
__global__ __launch_bounds__(256) void pack_vt(
    const ushort_t* __restrict__ Vbf, ushort_t* __restrict__ Vtp) {
  const int bid = blockIdx.x;
  const int pc = bid % 9;
  const int bk = bid / 9;
  const int tid = threadIdx.x;
  __shared__ ushort_t sT[64][264];
  {
    const int m = tid >> 2, jj = tid & 3;
    const int row = bk * HW_N + pc * 64 + m;
    const uint4* src = (const uint4*)&Vbf[row * E_N + jj * 64];
    uint4* d = (uint4*)&sT[m][jj * 64];
#pragma unroll
    for (int g = 0; g < 8; g++) d[g] = src[g];
  }
  __syncthreads();
  const int hh = tid >> 6, d = tid & 63;
  __attribute__((aligned(16))) ushort_t tmp[64];
#pragma unroll
  for (int j = 0; j < 64; j++)
    tmp[j] = sT[(j & 3) * 16 + (j >> 2)][hh * 64 + d];   // inverse perm gather
  const int chunk = (bk * 4 + hh) * 9 + pc;
  uint4* dst = (uint4*)&Vtp[chunk * 4096 + d * 64];
#pragma unroll
  for (int g = 0; g < 8; g++) dst[g] = ((const uint4*)tmp)[g];
}

// ---------------------------------------------------------------------------
// Flash-style slab cross attention v4: barrier-free, 1-wave blocks.
// grid 2304 = (hb 8 low: h,b) x (z 32) x (pb 9); 64 threads = 1 wave.
// Wave: one z, 64 q-rows (4 tiles). K/V B-frags direct from packed global.
// P store: key-permuted -> 4x ds_write_b64 per tile (no b16 scatter).
// ---------------------------------------------------------------------------
__global__ __launch_bounds__(64, 4) void attn_kernel(
    const ushort_t* __restrict__ Qbf, const ushort_t* __restrict__ Kpk,
    const ushort_t* __restrict__ Vtp, const float* __restrict__ topo,
    const float* __restrict__ lamp, const int* __restrict__ D0p,
    const int* __restrict__ slabp, float* __restrict__ O) {
  const int bid = blockIdx.x;
  const int hb = bid & 7;
  const int h = hb & 3, b = hb >> 2;
  const int z = (bid >> 3) & 31;
  const int pb = bid >> 8;                 // 0..8
  const int p0 = pb * 64;
  const int lane = threadIdx.x;
  const int quad = lane >> 4, col = lane & 15;

  const float LOG2E = 1.44269504f;
  const float lam2 = lamp[0] * LOG2E;
  const float S2 = 0.125f * LOG2E;
  const int D0 = D0p[0], slab = slabp[0];
  const float step = (float)(D0 - 1) / (float)(DZ_N - 1);
  int kkw;
  {
    int z0 = (int)floorf(fmaf((float)z, step, 0.5f));
    int kv = z0 / slab;
    kkw = kv < 0 ? 0 : (kv > K_N - 1 ? K_N - 1 : kv);
  }
  const int c_lo = (kkw - 1) < 0 ? 0 : (kkw - 1);
  const int c_hi = (kkw + 1) > (K_N - 1) ? (K_N - 1) : (kkw + 1);

  __shared__ ushort_t sP[64][72];   // [q-row][key'] pitch 72

  // Q A-fragments (once per wave): 4 q-tiles x K=64
  bf16x8 aq[4][2];
  const int qrow0 = (b * DZ_N + z) * HW_N + p0;
#pragma unroll
  for (int t = 0; t < 4; t++) {
    const ushort_t* qp = &Qbf[(qrow0 + t * 16 + col) * E_N + h * 64 + quad * 8];
    aq[t][0] = *(const bf16x8*)qp;
    aq[t][1] = *(const bf16x8*)(qp + 32);
  }

  f32x4 oacc[4][4];
#pragma unroll
  for (int t = 0; t < 4; t++)
#pragma unroll
    for (int dt = 0; dt < 4; dt++) oacc[t][dt] = (f32x4){0.f, 0.f, 0.f, 0.f};
  float lsum[4][4];
#pragma unroll
  for (int t = 0; t < 4; t++)
#pragma unroll
    for (int r = 0; r < 4; r++) lsum[t][r] = 0.f;

  for (int c = c_lo; c <= c_hi; c++) {
    const float biasE2 = ((c == kkw) ? -20.0f : -20.5f) * LOG2E;
    const ushort_t* cbase = Kpk + (size_t)(((b * K_N + c) * 4 + h) * 9) * 4096;
    const ushort_t* vbase = Vtp + (size_t)(((b * K_N + c) * 4 + h) * 9) * 4096;
    const float* topoc = &topo[(b * K_N + c) * HW_N + p0];
#pragma unroll 1
    for (int pc = 0; pc < 9; pc++) {
      const ushort_t* kc = cbase + pc * 4096;
      const ushort_t* vc = vbase + pc * 4096;
      bf16x8 bk[4][2], bv[4][2];
#pragma unroll
      for (int ct = 0; ct < 4; ct++) {
        const ushort_t* kp = kc + (ct * 16 + col) * 64 + quad * 8;
        bk[ct][0] = *(const bf16x8*)kp;
        bk[ct][1] = *(const bf16x8*)(kp + 32);
      }
#pragma unroll
      for (int dt = 0; dt < 4; dt++) {
        const ushort_t* vp = vc + (dt * 16 + col) * 64 + quad * 8;
        bv[dt][0] = *(const bf16x8*)vp;
        bv[dt][1] = *(const bf16x8*)(vp + 32);
      }

      const bool dflag = (pc == pb) && ((col >> 2) == quad);
      // ---- QK + softmax + permuted P store (b64) ----
#pragma unroll
      for (int t = 0; t < 4; t++) {
        f32x4 qk[4];
#pragma unroll
        for (int ct = 0; ct < 4; ct++) {
          f32x4 acc = (f32x4){0.f, 0.f, 0.f, 0.f};
          acc = __builtin_amdgcn_mfma_f32_16x16x32_bf16(aq[t][0], bk[ct][0], acc, 0, 0, 0);
          acc = __builtin_amdgcn_mfma_f32_16x16x32_bf16(aq[t][1], bk[ct][1], acc, 0, 0, 0);
          qk[ct] = acc;
        }
        const float tv2 = dflag ? lam2 * topoc[t * 16 + col] : 0.f;
#pragma unroll
        for (int r = 0; r < 4; r++) {
          float e[4];
#pragma unroll
          for (int ct = 0; ct < 4; ct++) {
            float x = fmaf(qk[ct][r], S2, biasE2);
            if (pc == pb && ct == t)
              x += ((col & 3) == r) ? tv2 : 0.f;
            e[ct] = __builtin_amdgcn_exp2f(x);
            lsum[t][r] += e[ct];
          }
          // pack 4 bf16 (truncate) -> one b64 store at key' = col*4 + ct
          unsigned lo = (__float_as_uint(e[0]) >> 16) |
                        (__float_as_uint(e[1]) & 0xFFFF0000u);
          unsigned hi = (__float_as_uint(e[2]) >> 16) |
                        (__float_as_uint(e[3]) & 0xFFFF0000u);
          *(uint2*)&sP[t * 16 + quad * 4 + r][col * 4] = (uint2){lo, hi};
        }
      }
      // ---- PV (keys in permuted space on both P and V) ----
      bf16x8 ap[4][2];
#pragma unroll
      for (int t = 0; t < 4; t++) {
        ap[t][0] = *(const bf16x8*)&sP[t * 16 + col][quad * 8];
        ap[t][1] = *(const bf16x8*)&sP[t * 16 + col][32 + quad * 8];
      }
#pragma unroll
      for (int dt = 0; dt < 4; dt++) {
#pragma unroll
        for (int t = 0; t < 4; t++) {
          oacc[t][dt] = __builtin_amdgcn_mfma_f32_16x16x32_bf16(ap[t][0], bv[dt][0], oacc[t][dt], 0, 0, 0);
          oacc[t][dt] = __builtin_amdgcn_mfma_f32_16x16x32_bf16(ap[t][1], bv[dt][1], oacc[t][dt], 0, 0, 0);
        }
      }
    }
  }

  // epilogue: l reduce over the quad's 16 lanes, O = oacc / l
#pragma unroll
  for (int t = 0; t < 4; t++)
#pragma unroll
    for (int r = 0; r < 4; r++) {
      float l = lsum[t][r];
      l += __shfl_xor(l, 1); l += __shfl_xor(l, 2);
      l += __shfl_xor(l, 4); l += __shfl_xor(l, 8);
      const float invl = 1.f / l;
      const int row = qrow0 + t * 16 + quad * 4 + r;
#pragma unroll
      for (int dt = 0; dt < 4; dt++)
        O[row * E_N + h * 64 + dt * 16 + col] = oacc[t][dt][r] * invl;
    }
}

// ---------------------------------------------------------------------------
// Output projection + residual (unchanged).
// ---------------------------------------------------------------------------
__global__ __launch_bounds__(256) void out_proj(
    const float* __restrict__ O, const float* __restrict__ Wp,
    const float* __restrict__ F3, float* __restrict__ outp) {
  __shared__ float sA[16][68];
  __shared__ float sW[16][128];
  __shared__ float sOut[64][129];
  const int tid = threadIdx.x;
  const int rowG = blockIdx.x * 64;
  float accv[8][4];
#pragma unroll
  for (int i = 0; i < 8; i++)
#pragma unroll
    for (int j = 0; j < 4; j++) accv[i][j] = 0.f;
  const int r0 = (tid >> 5) * 8;
  const int c0 = tid & 31;
  for (int k0 = 0; k0 < 256; k0 += 16) {
    if (k0) __syncthreads();
#pragma unroll
    for (int i = 0; i < 4; i++) {
      int idx = i * 256 + tid;
      int r = idx >> 4, kk = idx & 15;
      sA[kk][r] = O[(rowG + r) * E_N + k0 + kk];
    }
#pragma unroll
    for (int i = 0; i < 8; i++) {
      int idx = i * 256 + tid;
      int kk = idx >> 7, ccc = idx & 127;
      sW[kk][ccc] = Wp[(k0 + kk) * C3_N + ccc];
    }
    __syncthreads();
#pragma unroll 1
    for (int kk = 0; kk < 16; kk++) {
      float4 a0 = *(const float4*)&sA[kk][r0];
      float4 a1 = *(const float4*)&sA[kk][r0 + 4];
      float a[8] = {a0.x, a0.y, a0.z, a0.w, a1.x, a1.y, a1.z, a1.w};
#pragma unroll
      for (int j = 0; j < 4; j++) {
        float wv = sW[kk][c0 + 32 * j];
#pragma unroll
        for (int i = 0; i < 8; i++) accv[i][j] = fmaf(a[i], wv, accv[i][j]);
      }
    }
  }
  __syncthreads();
#pragma unroll
  for (int i = 0; i < 8; i++)
#pragma unroll
    for (int j = 0; j < 4; j++) sOut[r0 + i][c0 + 32 * j] = accv[i][j];
  __syncthreads();
  const int b = rowG / (DZ_N * HW_N);
  const int rem = rowG - b * DZ_N * HW_N;
  const int z = rem / HW_N;
  const int pp0 = rem - z * HW_N;
  const int pl = tid & 63, cg = tid >> 6;
  for (int cch = cg * 32; cch < cg * 32 + 32; cch++) {
    const int gidx = ((b * C3_N + cch) * DZ_N + z) * HW_N + pp0 + pl;
    outp[gidx] = F3[gidx] + sOut[pl][cch];
  }
}

// ---------------------------------------------------------------------------
extern "C" void kernel_launch(void* const* d_in, const int* in_sizes, int n_in,
                              void* d_out, int out_size, void* d_ws, size_t ws_size,
                              hipStream_t stream) {
  (void)in_sizes; (void)n_in; (void)out_size; (void)ws_size;
  const float* F3      = (const float*)d_in[0];
  const float* F2      = (const float*)d_in[1];
  const float* Wq      = (const float*)d_in[2];
  const float* Wk      = (const float*)d_in[3];
  const float* Wv      = (const float*)d_in[4];
  const float* Wp      = (const float*)d_in[5];
  const float* ln_q_g  = (const float*)d_in[6];
  const float* ln_q_b  = (const float*)d_in[7];
  const float* ln_kv_g = (const float*)d_in[8];
  const float* ln_kv_b = (const float*)d_in[9];
  const float* conv1_w = (const float*)d_in[10];
  const float* bn_g    = (const float*)d_in[11];
  const float* bn_b    = (const float*)d_in[12];
  const float* conv2_w = (const float*)d_in[13];
  const float* conv2_b = (const float*)d_in[14];
  const float* lam     = (const float*)d_in[15];
  const int*   D0      = (const int*)d_in[16];
  const int*   slab    = (const int*)d_in[17];
  float* out = (float*)d_out;

  char* ws = (char*)d_ws;
  size_t off = 0;
  auto alloc = [&](size_t bytes) {
    void* p = ws + off;
    off += (bytes + 255) & ~(size_t)255;
    return p;
  };
  const int QROWS = B_N * DZ_N * HW_N;   // 36864
  const int KVROWS = B_N * K_N * HW_N;   // 9216
  float* Qraw = (float*)alloc((size_t)QROWS * E_N * 4);   // -> reused as O
  float* Kraw = (float*)alloc((size_t)KVROWS * E_N * 4);  // Hp first
  float* Vraw = (float*)alloc((size_t)KVROWS * E_N * 4);  // -> Vtp
  ushort_t* Qbf = (ushort_t*)alloc((size_t)QROWS * E_N * 2);
  ushort_t* Kpk = (ushort_t*)alloc((size_t)KVROWS * E_N * 2);
  ushort_t* Vbf = (ushort_t*)alloc((size_t)KVROWS * E_N * 2);
  float* topo = (float*)alloc((size_t)B_N * K_N * HW_N * 4);
  float* Hp = Kraw;                    // dead before proj_gemm K runs
  ushort_t* Vtp = (ushort_t*)Vraw;     // Vraw dead after ln_bf16(V)
  float* O  = Qraw;                    // Qraw dead after ln_bf16(Q)

  // 1) topo branch
  topo_conv1<<<256, 384, 0, stream>>>(F2, conv1_w, Hp);
  topo_final<<<16, 576, 0, stream>>>(Hp, bn_g, bn_b, conv2_w, conv2_b, topo);
  // 2) projections (fp32); K/V col-split x2 for occupancy
  proj_gemm<128, 256><<<dim3(QROWS / 64, 1), 256, 0, stream>>>(
      F3, Wq, Qraw, DZ_N, C3_N * DZ_N * HW_N, HW_N, 1, DZ_N * HW_N);
  proj_gemm<96, 128><<<dim3(KVROWS / 64, 2), 256, 0, stream>>>(
      F2, Wk, Kraw, K_N, C2_N * HW_N * K_N, 1, K_N, HW_N * K_N);
  proj_gemm<96, 128><<<dim3(KVROWS / 64, 2), 256, 0, stream>>>(
      F2, Wv, Vraw, K_N, C2_N * HW_N * K_N, 1, K_N, HW_N * K_N);
  // 3) layernorm -> bf16 (K fused with packing)
  ln_bf16<<<QROWS / 4, 256, 0, stream>>>(Qraw, ln_q_g, ln_q_b, Qbf);
  ln_k_pack<<<KVROWS / 4, 256, 0, stream>>>(Kraw, ln_kv_g, ln_kv_b, Kpk);
  ln_bf16<<<KVROWS / 4, 256, 0, stream>>>(Vraw, ln_kv_g, ln_kv_b, Vbf);
  // 4) pack V^T (key-permuted layout)
  pack_vt<<<B_N * K_N * 9, 256, 0, stream>>>(Vbf, Vtp);
  // 5) attention (barrier-free, 1-wave blocks)
  attn_kernel<<<2304, 64, 0, stream>>>(
      Qbf, Kpk, Vtp, topo, lam, D0, slab, O);
  // 6) output projection + residual
  out_proj<<<QROWS / 64, 256, 0, stream>>>(O, Wp, F3, out);
}

// Round 5
// 737.442 us; speedup vs baseline: 1.1315x; 1.1315x over previous
//
#include <hip/hip_runtime.h>

typedef float f32x4 __attribute__((ext_vector_type(4)));
typedef __bf16 bf16x8 __attribute__((ext_vector_type(8)));
typedef unsigned short ushort_t;

#define DEV_INLINE __device__ __forceinline__

constexpr int B_N  = 2;
constexpr int C3_N = 128;
constexpr int C2_N = 96;
constexpr int DZ_N = 32;
constexpr int H_N  = 24;
constexpr int W_N  = 24;
constexpr int K_N  = 8;
constexpr int E_N  = 256;
constexpr int HW_N = 576;

DEV_INLINE unsigned short f2bf(float x) {
  union { float f; unsigned u; } v; v.f = x;
  unsigned r = v.u + 0x7FFFu + ((v.u >> 16) & 1u);
  return (unsigned short)(r >> 16);
}

// ---------------------------------------------------------------------------
// Topo kernel A: partial 3x3 conv (C2->64), split over 4 c-chunks of 24.
// ---------------------------------------------------------------------------
__global__ __launch_bounds__(384) void topo_conv1(
    const float* __restrict__ F2, const float* __restrict__ W1,
    float* __restrict__ Hp) {
  const int bid = blockIdx.x;
  const int cc = bid & 3;
  const int tg = (bid >> 2) & 3;
  const int bk = bid >> 4;           // 0..15 = b*8 + k
  const int b = bk >> 3, k = bk & 7;
  const int tid = threadIdx.x;
  const int y = tid >> 4;            // 0..23
  const int tq = tid & 15;           // 0..15

  __shared__ float simg[8][26][28];
  __shared__ float sw[16 * 97];

  float acc[24];
#pragma unroll
  for (int i = 0; i < 24; i++) acc[i] = 0.f;

  float* simgf = &simg[0][0][0];
  for (int i = tid; i < 8 * 26 * 28; i += 384) simgf[i] = 0.f;
  __syncthreads();

  for (int ch = 0; ch < 3; ch++) {
    if (ch) __syncthreads();
    const int c0 = cc * 24 + ch * 8;
    for (int i = tid; i < 8 * 24 * 24; i += 384) {
      int c = i / 576, p = i - c * 576;
      int yy = p / 24, xx = p - yy * 24;
      simg[c][yy + 1][xx + 1] =
          F2[(((b * C2_N + c0 + c) * H_N + yy) * W_N + xx) * K_N + k];
    }
    for (int i = tid; i < 16 * 72; i += 384) {
      int t2 = i / 72, rest = i - t2 * 72;
      int c = rest / 9, q = rest - c * 9;
      sw[t2 * 97 + c * 12 + q] =
          W1[(tg * 16 + t2) * (C2_N * 9) + (c0 + c) * 9 + q];
    }
    __syncthreads();
#pragma unroll 1
    for (int c = 0; c < 8; c++) {
      float w[9];
#pragma unroll
      for (int q = 0; q < 9; q++) w[q] = sw[tq * 97 + c * 12 + q];
#pragma unroll
      for (int dy = 0; dy < 3; dy++) {
        float r[26];
#pragma unroll
        for (int xx = 0; xx < 26; xx++) r[xx] = simg[c][y + dy][xx];
#pragma unroll
        for (int dx = 0; dx < 3; dx++) {
          float wv = w[dy * 3 + dx];
#pragma unroll
          for (int xx = 0; xx < 24; xx++)
            acc[xx] = fmaf(wv, r[xx + dx], acc[xx]);
        }
      }
    }
  }
  const int t = tg * 16 + tq;
  float* dst = &Hp[((cc * 16 + bk) * 64 + t) * HW_N + y * 24];
#pragma unroll
  for (int xx = 0; xx < 24; xx++) dst[xx] = acc[xx];
}

// ---------------------------------------------------------------------------
// Topo kernel B: sum partials, bn+relu, 1x1 conv, neighbor sum.
// ---------------------------------------------------------------------------
__global__ __launch_bounds__(576) void topo_final(
    const float* __restrict__ Hp, const float* __restrict__ bn_g,
    const float* __restrict__ bn_b, const float* __restrict__ W2,
    const float* __restrict__ b2, float* __restrict__ topo) {
  const int bk = blockIdx.x;
  const int p = threadIdx.x;
  __shared__ float pp[26][28];
  float* ppf = &pp[0][0];
  for (int i = p; i < 26 * 28; i += 576) ppf[i] = 0.f;

  const float inv = rsqrtf(1.0f + 1e-5f);
  float acc = b2[0];
  for (int t = 0; t < 64; t++) {
    float v = 0.f;
#pragma unroll
    for (int c4 = 0; c4 < 4; c4++)
      v += Hp[((c4 * 16 + bk) * 64 + t) * HW_N + p];
    float hcv = fmaxf(fmaf(bn_g[t] * inv, v, bn_b[t]), 0.f);
    acc = fmaf(W2[t], hcv, acc);
  }
  __syncthreads();
  pp[p / 24 + 1][p % 24 + 1] = acc;
  __syncthreads();
  const int yy = p / 24 + 1, xx = p % 24 + 1;
  float s = pp[yy-1][xx-1] + pp[yy-1][xx] + pp[yy-1][xx+1]
          + pp[yy][xx-1]                  + pp[yy][xx+1]
          + pp[yy+1][xx-1] + pp[yy+1][xx] + pp[yy+1][xx+1];
  topo[bk * HW_N + p] = acc + 0.5f * s;
}

// ---------------------------------------------------------------------------
// Projection GEMM (fp32 vector), templated on COLS with col-split grid.y.
// ---------------------------------------------------------------------------
template <int CIN, int COLS>
__global__ __launch_bounds__(256) void proj_gemm(
    const float* __restrict__ src, const float* __restrict__ Wm,
    float* __restrict__ outp, int outer, int bStride, int oStride,
    int pStride, int cStride) {
  __shared__ float sA[16][64];
  __shared__ float sW[16][COLS];
  __shared__ int sRB[64];
  const int tid = threadIdx.x;
  const int cb = blockIdx.y * COLS;
  if (tid < 64) {
    int rr = blockIdx.x * 64 + tid;
    int bb = rr / (outer * HW_N);
    int rem = rr - bb * outer * HW_N;
    int o = rem / HW_N;
    int p = rem - o * HW_N;
    sRB[tid] = bb * bStride + o * oStride + p * pStride;
  }
  __syncthreads();
  constexpr int NJ = COLS / 32;
  float accv[8][NJ];
#pragma unroll
  for (int i = 0; i < 8; i++)
#pragma unroll
    for (int j = 0; j < NJ; j++) accv[i][j] = 0.f;
  const int r0 = (tid >> 5) * 8;
  const int c0 = tid & 31;
  for (int k0 = 0; k0 < CIN; k0 += 16) {
    if (k0) __syncthreads();
#pragma unroll
    for (int i = 0; i < 4; i++) {
      int idx = i * 256 + tid;
      int kk = idx >> 6, r = idx & 63;
      sA[kk][r] = src[sRB[r] + (k0 + kk) * cStride];
    }
#pragma unroll
    for (int i = 0; i < 16 * COLS / 256; i++) {
      int idx = i * 256 + tid;
      int kk = idx / COLS, ccc = idx % COLS;
      sW[kk][ccc] = Wm[(k0 + kk) * E_N + cb + ccc];
    }
    __syncthreads();
#pragma unroll 1
    for (int kk = 0; kk < 16; kk++) {
      float4 a0 = *(const float4*)&sA[kk][r0];
      float4 a1 = *(const float4*)&sA[kk][r0 + 4];
      float a[8] = {a0.x, a0.y, a0.z, a0.w, a1.x, a1.y, a1.z, a1.w};
#pragma unroll
      for (int j = 0; j < NJ; j++) {
        float wv = sW[kk][c0 + 32 * j];
#pragma unroll
        for (int i = 0; i < 8; i++) accv[i][j] = fmaf(a[i], wv, accv[i][j]);
      }
    }
  }
  const int rowG = blockIdx.x * 64;
#pragma unroll
  for (int i = 0; i < 8; i++)
#pragma unroll
    for (int j = 0; j < NJ; j++)
      outp[(rowG + r0 + i) * E_N + cb + c0 + 32 * j] = accv[i][j];
}

// ---------------------------------------------------------------------------
// LayerNorm over E=256, fp32 in -> bf16 out (row-major). One wave per row.
// ---------------------------------------------------------------------------
__global__ __launch_bounds__(256) void ln_bf16(
    const float* __restrict__ src, const float* __restrict__ g,
    const float* __restrict__ bb, ushort_t* __restrict__ dst) {
  const int w = threadIdx.x >> 6, lane = threadIdx.x & 63;
  const int row = blockIdx.x * 4 + w;
  const float4 x = *(const float4*)&src[row * E_N + lane * 4];
  float s = x.x + x.y + x.z + x.w;
#pragma unroll
  for (int off = 32; off; off >>= 1) s += __shfl_xor(s, off);
  const float mean = s * (1.f / 256.f);
  float4 d = {x.x - mean, x.y - mean, x.z - mean, x.w - mean};
  float v = d.x * d.x + d.y * d.y + d.z * d.z + d.w * d.w;
#pragma unroll
  for (int off = 32; off; off >>= 1) v += __shfl_xor(v, off);
  const float rstd = rsqrtf(v * (1.f / 256.f) + 1e-5f);
  const float4 gv = *(const float4*)&g[lane * 4];
  const float4 bv = *(const float4*)&bb[lane * 4];
  ushort4 o;
  o.x = f2bf(fmaf(d.x * rstd, gv.x, bv.x));
  o.y = f2bf(fmaf(d.y * rstd, gv.y, bv.y));
  o.z = f2bf(fmaf(d.z * rstd, gv.z, bv.z));
  o.w = f2bf(fmaf(d.w * rstd, gv.w, bv.w));
  *(ushort4*)&dst[row * E_N + lane * 4] = o;
}

// ---------------------------------------------------------------------------
// ln_k_pack: LayerNorm K rows AND scatter into per-(bk,h,pc) packed chunk
// layout [m][d] (16B groups, plain order). One wave per row.
// ---------------------------------------------------------------------------
__global__ __launch_bounds__(256) void ln_k_pack(
    const float* __restrict__ src, const float* __restrict__ g,
    const float* __restrict__ bb, ushort_t* __restrict__ Kpk) {
  const int w = threadIdx.x >> 6, lane = threadIdx.x & 63;
  const int row = blockIdx.x * 4 + w;
  const float4 x = *(const float4*)&src[row * E_N + lane * 4];
  float s = x.x + x.y + x.z + x.w;
#pragma unroll
  for (int off = 32; off; off >>= 1) s += __shfl_xor(s, off);
  const float mean = s * (1.f / 256.f);
  float4 d = {x.x - mean, x.y - mean, x.z - mean, x.w - mean};
  float v = d.x * d.x + d.y * d.y + d.z * d.z + d.w * d.w;
#pragma unroll
  for (int off = 32; off; off >>= 1) v += __shfl_xor(v, off);
  const float rstd = rsqrtf(v * (1.f / 256.f) + 1e-5f);
  const float4 gv = *(const float4*)&g[lane * 4];
  const float4 bv = *(const float4*)&bb[lane * 4];
  ushort4 o;
  o.x = f2bf(fmaf(d.x * rstd, gv.x, bv.x));
  o.y = f2bf(fmaf(d.y * rstd, gv.y, bv.y));
  o.z = f2bf(fmaf(d.z * rstd, gv.z, bv.z));
  o.w = f2bf(fmaf(d.w * rstd, gv.w, bv.w));
  const int bk = row / HW_N;
  const int p = row - bk * HW_N;
  const int pc = p >> 6, m = p & 63;
  const int h = lane >> 4;
  const int dcol = (lane * 4) & 63;
  ushort_t* dst = &Kpk[(((bk * 4 + h) * 9 + pc) * 4096) + m * 64 + dcol];
  *(ushort4*)dst = o;
}

// ---------------------------------------------------------------------------
// pack_vt: Vbf rows -> transposed per-(bk,h,pc) 8KB chunks [d][m'] where the
// key dim is PERMUTED: m' = (m&15)*4 + (m>>4). Makes the attn P-store
// contiguous (b64) while keeping A-frag reads b128. PV sums over keys, so a
// consistent permutation of P-columns and V-rows is exact.
// ---------------------------------------------------------------------------
__global__ __launch_bounds__(256) void pack_vt(
    const ushort_t* __restrict__ Vbf, ushort_t* __restrict__ Vtp) {
  const int bid = blockIdx.x;
  const int pc = bid % 9;
  const int bk = bid / 9;
  const int tid = threadIdx.x;
  __shared__ ushort_t sT[64][264];
  {
    const int m = tid >> 2, jj = tid & 3;
    const int row = bk * HW_N + pc * 64 + m;
    const uint4* src = (const uint4*)&Vbf[row * E_N + jj * 64];
    uint4* d = (uint4*)&sT[m][jj * 64];
#pragma unroll
    for (int g = 0; g < 8; g++) d[g] = src[g];
  }
  __syncthreads();
  const int hh = tid >> 6, d = tid & 63;
  __attribute__((aligned(16))) ushort_t tmp[64];
#pragma unroll
  for (int j = 0; j < 64; j++)
    tmp[j] = sT[(j & 3) * 16 + (j >> 2)][hh * 64 + d];   // inverse perm gather
  const int chunk = (bk * 4 + hh) * 9 + pc;
  uint4* dst = (uint4*)&Vtp[chunk * 4096 + d * 64];
#pragma unroll
  for (int g = 0; g < 8; g++) dst[g] = ((const uint4*)tmp)[g];
}

// ---------------------------------------------------------------------------
// Flash-style slab cross attention v5: barrier-free, 4-wave blocks,
// wave = ONE 16-row q-tile of one z (small register footprint, no spill).
// grid 2304 = (hb 8 low: h,b) x (z 32) x (pb 9); 256 thr = 4 waves.
// K/V B-frags direct from packed global (L1-multicast across the 4 waves).
// P store: key-permuted -> 4x ds_write_b64 per chunk (no b16 scatter).
// ---------------------------------------------------------------------------
__global__ __launch_bounds__(256, 4) void attn_kernel(
    const ushort_t* __restrict__ Qbf, const ushort_t* __restrict__ Kpk,
    const ushort_t* __restrict__ Vtp, const float* __restrict__ topo,
    const float* __restrict__ lamp, const int* __restrict__ D0p,
    const int* __restrict__ slabp, float* __restrict__ O) {
  const int bid = blockIdx.x;
  const int hb = bid & 7;
  const int h = hb & 3, b = hb >> 2;
  const int z = (bid >> 3) & 31;
  const int pb = bid >> 8;                 // 0..8
  const int p0 = pb * 64;
  const int tid = threadIdx.x;
  const int t = tid >> 6;                  // wave = q-tile index 0..3
  const int lane = tid & 63;
  const int quad = lane >> 4, col = lane & 15;

  const float LOG2E = 1.44269504f;
  const float lam2 = lamp[0] * LOG2E;
  const float S2 = 0.125f * LOG2E;
  const int D0 = D0p[0], slab = slabp[0];
  const float step = (float)(D0 - 1) / (float)(DZ_N - 1);
  int kkw;
  {
    int z0 = (int)floorf(fmaf((float)z, step, 0.5f));
    int kv = z0 / slab;
    kkw = kv < 0 ? 0 : (kv > K_N - 1 ? K_N - 1 : kv);
  }
  const int c_lo = (kkw - 1) < 0 ? 0 : (kkw - 1);
  const int c_hi = (kkw + 1) > (K_N - 1) ? (K_N - 1) : (kkw + 1);

  __shared__ ushort_t sP[4][16][72];   // per-wave P round-trip (16-B aligned rows)

  // Q A-fragment for this wave's tile only (8 VGPRs)
  const int qrow0 = (b * DZ_N + z) * HW_N + p0;
  const ushort_t* qp = &Qbf[(qrow0 + t * 16 + col) * E_N + h * 64 + quad * 8];
  const bf16x8 aq0 = *(const bf16x8*)qp;
  const bf16x8 aq1 = *(const bf16x8*)(qp + 32);

  f32x4 oacc[4];
#pragma unroll
  for (int dt = 0; dt < 4; dt++) oacc[dt] = (f32x4){0.f, 0.f, 0.f, 0.f};
  float lsum[4] = {0.f, 0.f, 0.f, 0.f};

  for (int c = c_lo; c <= c_hi; c++) {
    const float biasE2 = ((c == kkw) ? -20.0f : -20.5f) * LOG2E;
    const ushort_t* cbase = Kpk + (size_t)(((b * K_N + c) * 4 + h) * 9) * 4096;
    const ushort_t* vbase = Vtp + (size_t)(((b * K_N + c) * 4 + h) * 9) * 4096;
    const float* topoc = &topo[(b * K_N + c) * HW_N + p0];
#pragma unroll 1
    for (int pc = 0; pc < 9; pc++) {
      const ushort_t* kc = cbase + pc * 4096;
      const ushort_t* vc = vbase + pc * 4096;

      // ---- QK: load K frags, 8 MFMAs ----
      f32x4 qk[4];
#pragma unroll
      for (int ct = 0; ct < 4; ct++) {
        const ushort_t* kp = kc + (ct * 16 + col) * 64 + quad * 8;
        bf16x8 bk0 = *(const bf16x8*)kp;
        bf16x8 bk1 = *(const bf16x8*)(kp + 32);
        f32x4 acc = (f32x4){0.f, 0.f, 0.f, 0.f};
        acc = __builtin_amdgcn_mfma_f32_16x16x32_bf16(aq0, bk0, acc, 0, 0, 0);
        acc = __builtin_amdgcn_mfma_f32_16x16x32_bf16(aq1, bk1, acc, 0, 0, 0);
        qk[ct] = acc;
      }

      // ---- softmax (fixed-max, exp2 domain) + permuted b64 P store ----
      const bool dflag = (pc == pb) && ((col >> 2) == quad);
      const float tv2 = dflag ? lam2 * topoc[t * 16 + col] : 0.f;
#pragma unroll
      for (int r = 0; r < 4; r++) {
        float e[4];
#pragma unroll
        for (int ct = 0; ct < 4; ct++) {
          float x = fmaf(qk[ct][r], S2, biasE2);
          if (pc == pb && ct == t)
            x += ((col & 3) == r) ? tv2 : 0.f;
          e[ct] = __builtin_amdgcn_exp2f(x);
          lsum[r] += e[ct];
        }
        unsigned lo = (__float_as_uint(e[0]) >> 16) |
                      (__float_as_uint(e[1]) & 0xFFFF0000u);
        unsigned hi = (__float_as_uint(e[2]) >> 16) |
                      (__float_as_uint(e[3]) & 0xFFFF0000u);
        *(uint2*)&sP[t][quad * 4 + r][col * 4] = (uint2){lo, hi};
      }

      // ---- PV: load V frags (permuted key space), 8 MFMAs ----
      const bf16x8 ap0 = *(const bf16x8*)&sP[t][col][quad * 8];
      const bf16x8 ap1 = *(const bf16x8*)&sP[t][col][32 + quad * 8];
#pragma unroll
      for (int dt = 0; dt < 4; dt++) {
        const ushort_t* vp = vc + (dt * 16 + col) * 64 + quad * 8;
        bf16x8 bv0 = *(const bf16x8*)vp;
        bf16x8 bv1 = *(const bf16x8*)(vp + 32);
        oacc[dt] = __builtin_amdgcn_mfma_f32_16x16x32_bf16(ap0, bv0, oacc[dt], 0, 0, 0);
        oacc[dt] = __builtin_amdgcn_mfma_f32_16x16x32_bf16(ap1, bv1, oacc[dt], 0, 0, 0);
      }
    }
  }

  // epilogue: l reduce over the quad's 16 lanes, O = oacc / l
#pragma unroll
  for (int r = 0; r < 4; r++) {
    float l = lsum[r];
    l += __shfl_xor(l, 1); l += __shfl_xor(l, 2);
    l += __shfl_xor(l, 4); l += __shfl_xor(l, 8);
    const float invl = 1.f / l;
    const int row = qrow0 + t * 16 + quad * 4 + r;
#pragma unroll
    for (int dt = 0; dt < 4; dt++)
      O[row * E_N + h * 64 + dt * 16 + col] = oacc[dt][r] * invl;
  }
}

// ---------------------------------------------------------------------------
// Output projection + residual (unchanged).
// ---------------------------------------------------------------------------
__global__ __launch_bounds__(256) void out_proj(
    const float* __restrict__ O, const float* __restrict__ Wp,
    const float* __restrict__ F3, float* __restrict__ outp) {
  __shared__ float sA[16][68];
  __shared__ float sW[16][128];
  __shared__ float sOut[64][129];
  const int tid = threadIdx.x;
  const int rowG = blockIdx.x * 64;
  float accv[8][4];
#pragma unroll
  for (int i = 0; i < 8; i++)
#pragma unroll
    for (int j = 0; j < 4; j++) accv[i][j] = 0.f;
  const int r0 = (tid >> 5) * 8;
  const int c0 = tid & 31;
  for (int k0 = 0; k0 < 256; k0 += 16) {
    if (k0) __syncthreads();
#pragma unroll
    for (int i = 0; i < 4; i++) {
      int idx = i * 256 + tid;
      int r = idx >> 4, kk = idx & 15;
      sA[kk][r] = O[(rowG + r) * E_N + k0 + kk];
    }
#pragma unroll
    for (int i = 0; i < 8; i++) {
      int idx = i * 256 + tid;
      int kk = idx >> 7, ccc = idx & 127;
      sW[kk][ccc] = Wp[(k0 + kk) * C3_N + ccc];
    }
    __syncthreads();
#pragma unroll 1
    for (int kk = 0; kk < 16; kk++) {
      float4 a0 = *(const float4*)&sA[kk][r0];
      float4 a1 = *(const float4*)&sA[kk][r0 + 4];
      float a[8] = {a0.x, a0.y, a0.z, a0.w, a1.x, a1.y, a1.z, a1.w};
#pragma unroll
      for (int j = 0; j < 4; j++) {
        float wv = sW[kk][c0 + 32 * j];
#pragma unroll
        for (int i = 0; i < 8; i++) accv[i][j] = fmaf(a[i], wv, accv[i][j]);
      }
    }
  }
  __syncthreads();
#pragma unroll
  for (int i = 0; i < 8; i++)
#pragma unroll
    for (int j = 0; j < 4; j++) sOut[r0 + i][c0 + 32 * j] = accv[i][j];
  __syncthreads();
  const int b = rowG / (DZ_N * HW_N);
  const int rem = rowG - b * DZ_N * HW_N;
  const int z = rem / HW_N;
  const int pp0 = rem - z * HW_N;
  const int pl = tid & 63, cg = tid >> 6;
  for (int cch = cg * 32; cch < cg * 32 + 32; cch++) {
    const int gidx = ((b * C3_N + cch) * DZ_N + z) * HW_N + pp0 + pl;
    outp[gidx] = F3[gidx] + sOut[pl][cch];
  }
}

// ---------------------------------------------------------------------------
extern "C" void kernel_launch(void* const* d_in, const int* in_sizes, int n_in,
                              void* d_out, int out_size, void* d_ws, size_t ws_size,
                              hipStream_t stream) {
  (void)in_sizes; (void)n_in; (void)out_size; (void)ws_size;
  const float* F3      = (const float*)d_in[0];
  const float* F2      = (const float*)d_in[1];
  const float* Wq      = (const float*)d_in[2];
  const float* Wk      = (const float*)d_in[3];
  const float* Wv      = (const float*)d_in[4];
  const float* Wp      = (const float*)d_in[5];
  const float* ln_q_g  = (const float*)d_in[6];
  const float* ln_q_b  = (const float*)d_in[7];
  const float* ln_kv_g = (const float*)d_in[8];
  const float* ln_kv_b = (const float*)d_in[9];
  const float* conv1_w = (const float*)d_in[10];
  const float* bn_g    = (const float*)d_in[11];
  const float* bn_b    = (const float*)d_in[12];
  const float* conv2_w = (const float*)d_in[13];
  const float* conv2_b = (const float*)d_in[14];
  const float* lam     = (const float*)d_in[15];
  const int*   D0      = (const int*)d_in[16];
  const int*   slab    = (const int*)d_in[17];
  float* out = (float*)d_out;

  char* ws = (char*)d_ws;
  size_t off = 0;
  auto alloc = [&](size_t bytes) {
    void* p = ws + off;
    off += (bytes + 255) & ~(size_t)255;
    return p;
  };
  const int QROWS = B_N * DZ_N * HW_N;   // 36864
  const int KVROWS = B_N * K_N * HW_N;   // 9216
  float* Qraw = (float*)alloc((size_t)QROWS * E_N * 4);   // -> reused as O
  float* Kraw = (float*)alloc((size_t)KVROWS * E_N * 4);  // Hp first
  float* Vraw = (float*)alloc((size_t)KVROWS * E_N * 4);  // -> Vtp
  ushort_t* Qbf = (ushort_t*)alloc((size_t)QROWS * E_N * 2);
  ushort_t* Kpk = (ushort_t*)alloc((size_t)KVROWS * E_N * 2);
  ushort_t* Vbf = (ushort_t*)alloc((size_t)KVROWS * E_N * 2);
  float* topo = (float*)alloc((size_t)B_N * K_N * HW_N * 4);
  float* Hp = Kraw;                    // dead before proj_gemm K runs
  ushort_t* Vtp = (ushort_t*)Vraw;     // Vraw dead after ln_bf16(V)
  float* O  = Qraw;                    // Qraw dead after ln_bf16(Q)

  // 1) topo branch
  topo_conv1<<<256, 384, 0, stream>>>(F2, conv1_w, Hp);
  topo_final<<<16, 576, 0, stream>>>(Hp, bn_g, bn_b, conv2_w, conv2_b, topo);
  // 2) projections (fp32); K/V col-split x2 for occupancy
  proj_gemm<128, 256><<<dim3(QROWS / 64, 1), 256, 0, stream>>>(
      F3, Wq, Qraw, DZ_N, C3_N * DZ_N * HW_N, HW_N, 1, DZ_N * HW_N);
  proj_gemm<96, 128><<<dim3(KVROWS / 64, 2), 256, 0, stream>>>(
      F2, Wk, Kraw, K_N, C2_N * HW_N * K_N, 1, K_N, HW_N * K_N);
  proj_gemm<96, 128><<<dim3(KVROWS / 64, 2), 256, 0, stream>>>(
      F2, Wv, Vraw, K_N, C2_N * HW_N * K_N, 1, K_N, HW_N * K_N);
  // 3) layernorm -> bf16 (K fused with packing)
  ln_bf16<<<QROWS / 4, 256, 0, stream>>>(Qraw, ln_q_g, ln_q_b, Qbf);
  ln_k_pack<<<KVROWS / 4, 256, 0, stream>>>(Kraw, ln_kv_g, ln_kv_b, Kpk);
  ln_bf16<<<KVROWS / 4, 256, 0, stream>>>(Vraw, ln_kv_g, ln_kv_b, Vbf);
  // 4) pack V^T (key-permuted layout)
  pack_vt<<<B_N * K_N * 9, 256, 0, stream>>>(Vbf, Vtp);
  // 5) attention (barrier-free, 4-wave blocks, 1 q-tile per wave)
  attn_kernel<<<2304, 256, 0, stream>>>(
      Qbf, Kpk, Vtp, topo, lam, D0, slab, O);
  // 6) output projection + residual
  out_proj<<<QROWS / 64, 256, 0, stream>>>(O, Wp, F3, out);
}

// Round 6
// 481.420 us; speedup vs baseline: 1.7332x; 1.5318x over previous
//
#include <hip/hip_runtime.h>

typedef float f32x4 __attribute__((ext_vector_type(4)));
typedef __bf16 bf16x8 __attribute__((ext_vector_type(8)));
typedef unsigned short ushort_t;

#define DEV_INLINE __device__ __forceinline__

constexpr int B_N  = 2;
constexpr int C3_N = 128;
constexpr int C2_N = 96;
constexpr int DZ_N = 32;
constexpr int H_N  = 24;
constexpr int W_N  = 24;
constexpr int K_N  = 8;
constexpr int E_N  = 256;
constexpr int HW_N = 576;

DEV_INLINE unsigned short f2bf(float x) {
  union { float f; unsigned u; } v; v.f = x;
  unsigned r = v.u + 0x7FFFu + ((v.u >> 16) & 1u);
  return (unsigned short)(r >> 16);
}

// ---------------------------------------------------------------------------
// Topo kernel A: partial 3x3 conv (C2->64), split over 4 c-chunks of 24.
// ---------------------------------------------------------------------------
__global__ __launch_bounds__(384) void topo_conv1(
    const float* __restrict__ F2, const float* __restrict__ W1,
    float* __restrict__ Hp) {
  const int bid = blockIdx.x;
  const int cc = bid & 3;
  const int tg = (bid >> 2) & 3;
  const int bk = bid >> 4;           // 0..15 = b*8 + k
  const int b = bk >> 3, k = bk & 7;
  const int tid = threadIdx.x;
  const int y = tid >> 4;            // 0..23
  const int tq = tid & 15;           // 0..15

  __shared__ float simg[8][26][28];
  __shared__ float sw[16 * 97];

  float acc[24];
#pragma unroll
  for (int i = 0; i < 24; i++) acc[i] = 0.f;

  float* simgf = &simg[0][0][0];
  for (int i = tid; i < 8 * 26 * 28; i += 384) simgf[i] = 0.f;
  __syncthreads();

  for (int ch = 0; ch < 3; ch++) {
    if (ch) __syncthreads();
    const int c0 = cc * 24 + ch * 8;
    for (int i = tid; i < 8 * 24 * 24; i += 384) {
      int c = i / 576, p = i - c * 576;
      int yy = p / 24, xx = p - yy * 24;
      simg[c][yy + 1][xx + 1] =
          F2[(((b * C2_N + c0 + c) * H_N + yy) * W_N + xx) * K_N + k];
    }
    for (int i = tid; i < 16 * 72; i += 384) {
      int t2 = i / 72, rest = i - t2 * 72;
      int c = rest / 9, q = rest - c * 9;
      sw[t2 * 97 + c * 12 + q] =
          W1[(tg * 16 + t2) * (C2_N * 9) + (c0 + c) * 9 + q];
    }
    __syncthreads();
#pragma unroll 1
    for (int c = 0; c < 8; c++) {
      float w[9];
#pragma unroll
      for (int q = 0; q < 9; q++) w[q] = sw[tq * 97 + c * 12 + q];
#pragma unroll
      for (int dy = 0; dy < 3; dy++) {
        float r[26];
#pragma unroll
        for (int xx = 0; xx < 26; xx++) r[xx] = simg[c][y + dy][xx];
#pragma unroll
        for (int dx = 0; dx < 3; dx++) {
          float wv = w[dy * 3 + dx];
#pragma unroll
          for (int xx = 0; xx < 24; xx++)
            acc[xx] = fmaf(wv, r[xx + dx], acc[xx]);
        }
      }
    }
  }
  const int t = tg * 16 + tq;
  float* dst = &Hp[((cc * 16 + bk) * 64 + t) * HW_N + y * 24];
#pragma unroll
  for (int xx = 0; xx < 24; xx++) dst[xx] = acc[xx];
}

// ---------------------------------------------------------------------------
// Topo kernel B: sum partials, bn+relu, 1x1 conv, neighbor sum.
// ---------------------------------------------------------------------------
__global__ __launch_bounds__(576) void topo_final(
    const float* __restrict__ Hp, const float* __restrict__ bn_g,
    const float* __restrict__ bn_b, const float* __restrict__ W2,
    const float* __restrict__ b2, float* __restrict__ topo) {
  const int bk = blockIdx.x;
  const int p = threadIdx.x;
  __shared__ float pp[26][28];
  float* ppf = &pp[0][0];
  for (int i = p; i < 26 * 28; i += 576) ppf[i] = 0.f;

  const float inv = rsqrtf(1.0f + 1e-5f);
  float acc = b2[0];
  for (int t = 0; t < 64; t++) {
    float v = 0.f;
#pragma unroll
    for (int c4 = 0; c4 < 4; c4++)
      v += Hp[((c4 * 16 + bk) * 64 + t) * HW_N + p];
    float hcv = fmaxf(fmaf(bn_g[t] * inv, v, bn_b[t]), 0.f);
    acc = fmaf(W2[t], hcv, acc);
  }
  __syncthreads();
  pp[p / 24 + 1][p % 24 + 1] = acc;
  __syncthreads();
  const int yy = p / 24 + 1, xx = p % 24 + 1;
  float s = pp[yy-1][xx-1] + pp[yy-1][xx] + pp[yy-1][xx+1]
          + pp[yy][xx-1]                  + pp[yy][xx+1]
          + pp[yy+1][xx-1] + pp[yy+1][xx] + pp[yy+1][xx+1];
  topo[bk * HW_N + p] = acc + 0.5f * s;
}

// ---------------------------------------------------------------------------
// Projection GEMM (fp32 vector), templated on COLS with col-split grid.y.
// ---------------------------------------------------------------------------
template <int CIN, int COLS>
__global__ __launch_bounds__(256) void proj_gemm(
    const float* __restrict__ src, const float* __restrict__ Wm,
    float* __restrict__ outp, int outer, int bStride, int oStride,
    int pStride, int cStride) {
  __shared__ float sA[16][64];
  __shared__ float sW[16][COLS];
  __shared__ int sRB[64];
  const int tid = threadIdx.x;
  const int cb = blockIdx.y * COLS;
  if (tid < 64) {
    int rr = blockIdx.x * 64 + tid;
    int bb = rr / (outer * HW_N);
    int rem = rr - bb * outer * HW_N;
    int o = rem / HW_N;
    int p = rem - o * HW_N;
    sRB[tid] = bb * bStride + o * oStride + p * pStride;
  }
  __syncthreads();
  constexpr int NJ = COLS / 32;
  float accv[8][NJ];
#pragma unroll
  for (int i = 0; i < 8; i++)
#pragma unroll
    for (int j = 0; j < NJ; j++) accv[i][j] = 0.f;
  const int r0 = (tid >> 5) * 8;
  const int c0 = tid & 31;
  for (int k0 = 0; k0 < CIN; k0 += 16) {
    if (k0) __syncthreads();
#pragma unroll
    for (int i = 0; i < 4; i++) {
      int idx = i * 256 + tid;
      int kk = idx >> 6, r = idx & 63;
      sA[kk][r] = src[sRB[r] + (k0 + kk) * cStride];
    }
#pragma unroll
    for (int i = 0; i < 16 * COLS / 256; i++) {
      int idx = i * 256 + tid;
      int kk = idx / COLS, ccc = idx % COLS;
      sW[kk][ccc] = Wm[(k0 + kk) * E_N + cb + ccc];
    }
    __syncthreads();
#pragma unroll 1
    for (int kk = 0; kk < 16; kk++) {
      float4 a0 = *(const float4*)&sA[kk][r0];
      float4 a1 = *(const float4*)&sA[kk][r0 + 4];
      float a[8] = {a0.x, a0.y, a0.z, a0.w, a1.x, a1.y, a1.z, a1.w};
#pragma unroll
      for (int j = 0; j < NJ; j++) {
        float wv = sW[kk][c0 + 32 * j];
#pragma unroll
        for (int i = 0; i < 8; i++) accv[i][j] = fmaf(a[i], wv, accv[i][j]);
      }
    }
  }
  const int rowG = blockIdx.x * 64;
#pragma unroll
  for (int i = 0; i < 8; i++)
#pragma unroll
    for (int j = 0; j < NJ; j++)
      outp[(rowG + r0 + i) * E_N + cb + c0 + 32 * j] = accv[i][j];
}

// ---------------------------------------------------------------------------
// LayerNorm over E=256, fp32 in -> bf16 out (row-major). One wave per row.
// ---------------------------------------------------------------------------
__global__ __launch_bounds__(256) void ln_bf16(
    const float* __restrict__ src, const float* __restrict__ g,
    const float* __restrict__ bb, ushort_t* __restrict__ dst) {
  const int w = threadIdx.x >> 6, lane = threadIdx.x & 63;
  const int row = blockIdx.x * 4 + w;
  const float4 x = *(const float4*)&src[row * E_N + lane * 4];
  float s = x.x + x.y + x.z + x.w;
#pragma unroll
  for (int off = 32; off; off >>= 1) s += __shfl_xor(s, off);
  const float mean = s * (1.f / 256.f);
  float4 d = {x.x - mean, x.y - mean, x.z - mean, x.w - mean};
  float v = d.x * d.x + d.y * d.y + d.z * d.z + d.w * d.w;
#pragma unroll
  for (int off = 32; off; off >>= 1) v += __shfl_xor(v, off);
  const float rstd = rsqrtf(v * (1.f / 256.f) + 1e-5f);
  const float4 gv = *(const float4*)&g[lane * 4];
  const float4 bv = *(const float4*)&bb[lane * 4];
  ushort4 o;
  o.x = f2bf(fmaf(d.x * rstd, gv.x, bv.x));
  o.y = f2bf(fmaf(d.y * rstd, gv.y, bv.y));
  o.z = f2bf(fmaf(d.z * rstd, gv.z, bv.z));
  o.w = f2bf(fmaf(d.w * rstd, gv.w, bv.w));
  *(ushort4*)&dst[row * E_N + lane * 4] = o;
}

// ---------------------------------------------------------------------------
// ln_k_pack: LayerNorm K rows AND scatter into per-(bk,h,pc) packed chunk
// [m][d] with 16B groups XOR-swizzled by (m&7) -> conflict-free LDS B-reads.
// ---------------------------------------------------------------------------
__global__ __launch_bounds__(256) void ln_k_pack(
    const float* __restrict__ src, const float* __restrict__ g,
    const float* __restrict__ bb, ushort_t* __restrict__ Kpk) {
  const int w = threadIdx.x >> 6, lane = threadIdx.x & 63;
  const int row = blockIdx.x * 4 + w;
  const float4 x = *(const float4*)&src[row * E_N + lane * 4];
  float s = x.x + x.y + x.z + x.w;
#pragma unroll
  for (int off = 32; off; off >>= 1) s += __shfl_xor(s, off);
  const float mean = s * (1.f / 256.f);
  float4 d = {x.x - mean, x.y - mean, x.z - mean, x.w - mean};
  float v = d.x * d.x + d.y * d.y + d.z * d.z + d.w * d.w;
#pragma unroll
  for (int off = 32; off; off >>= 1) v += __shfl_xor(v, off);
  const float rstd = rsqrtf(v * (1.f / 256.f) + 1e-5f);
  const float4 gv = *(const float4*)&g[lane * 4];
  const float4 bv = *(const float4*)&bb[lane * 4];
  ushort4 o;
  o.x = f2bf(fmaf(d.x * rstd, gv.x, bv.x));
  o.y = f2bf(fmaf(d.y * rstd, gv.y, bv.y));
  o.z = f2bf(fmaf(d.z * rstd, gv.z, bv.z));
  o.w = f2bf(fmaf(d.w * rstd, gv.w, bv.w));
  const int bk = row / HW_N;
  const int p = row - bk * HW_N;
  const int pc = p >> 6, m = p & 63;
  const int h = lane >> 4;
  const int dcol = (lane * 4) & 63;
  const int grp = (dcol >> 3) ^ (m & 7);           // XOR swizzle 16B groups
  const int idx = m * 64 + grp * 8 + (dcol & 7);
  ushort_t* dst = &Kpk[(((bk * 4 + h) * 9 + pc) * 4096) + idx];
  *(ushort4*)dst = o;
}

// ---------------------------------------------------------------------------
// pack_vt: Vbf -> per-(bk,h,pc) 8KB chunks [d][m'] with key dim PERMUTED
// m' = (m&15)*4 + (m>>4) (for b64 P-stores) AND 16B groups XOR-swizzled by
// (d&7) (for conflict-free LDS B-reads).
// ---------------------------------------------------------------------------
__global__ __launch_bounds__(256) void pack_vt(
    const ushort_t* __restrict__ Vbf, ushort_t* __restrict__ Vtp) {
  const int bid = blockIdx.x;
  const int pc = bid % 9;
  const int bk = bid / 9;
  const int tid = threadIdx.x;
  __shared__ ushort_t sT[64][264];
  {
    const int m = tid >> 2, jj = tid & 3;
    const int row = bk * HW_N + pc * 64 + m;
    const uint4* src = (const uint4*)&Vbf[row * E_N + jj * 64];
    uint4* d = (uint4*)&sT[m][jj * 64];
#pragma unroll
    for (int g = 0; g < 8; g++) d[g] = src[g];
  }
  __syncthreads();
  const int hh = tid >> 6, d = tid & 63;
  __attribute__((aligned(16))) ushort_t tmp[64];
#pragma unroll
  for (int j = 0; j < 64; j++)
    tmp[j] = sT[(j & 3) * 16 + (j >> 2)][hh * 64 + d];   // inverse perm gather
  const int chunk = (bk * 4 + hh) * 9 + pc;
  uint4* dst = (uint4*)&Vtp[chunk * 4096 + d * 64];
  const int sw = d & 7;
#pragma unroll
  for (int g = 0; g < 8; g++) dst[g ^ sw] = ((const uint4*)tmp)[g];
}

// ---------------------------------------------------------------------------
// Flash-style slab cross attention v6: R2 skeleton + reg-prefetch pipeline.
// grid 1152 = (hb 8 low: h,b) x (zp 16) x (pb 9); 256 thr = 4 waves.
// Wave w: z = 2*zp + (w>>1), 32 q-rows (2 tiles) at p0 + (w&1)*32.
// Per chunk: commit prefetched regs -> LDS, prefetch next chunk to regs,
// compute from LDS (swizzled conflict-free B-frags, b64 permuted P-store).
// ---------------------------------------------------------------------------
__global__ __launch_bounds__(256) void attn_kernel(
    const ushort_t* __restrict__ Qbf, const ushort_t* __restrict__ Kpk,
    const ushort_t* __restrict__ Vtp, const float* __restrict__ topo,
    const float* __restrict__ lamp, const int* __restrict__ D0p,
    const int* __restrict__ slabp, float* __restrict__ O) {
  const int bid = blockIdx.x;
  const int hb = bid & 7;
  const int h = hb & 3, b = hb >> 2;
  const int zp = (bid >> 3) & 15;
  const int pb = bid >> 7;                 // 0..8
  const int p0 = pb * 64;
  const int tid = threadIdx.x;
  const int w = tid >> 6, lane = tid & 63;
  const int quad = lane >> 4, col = lane & 15;
  const int z = zp * 2 + (w >> 1);
  const int th = w & 1;

  const float LOG2E = 1.44269504f;
  const float lam2 = lamp[0] * LOG2E;
  const float S2 = 0.125f * LOG2E;
  const int D0 = D0p[0], slab = slabp[0];
  const float step = (float)(D0 - 1) / (float)(DZ_N - 1);

  int kkw, kka, kkb;
  {
    int z0 = (int)floorf(fmaf((float)z, step, 0.5f));
    int kv = z0 / slab;
    kkw = kv < 0 ? 0 : (kv > K_N - 1 ? K_N - 1 : kv);
    int z0a = (int)floorf(fmaf((float)(zp * 2), step, 0.5f));
    int z0b = (int)floorf(fmaf((float)(zp * 2 + 1), step, 0.5f));
    int ka = z0a / slab; ka = ka < 0 ? 0 : (ka > K_N - 1 ? K_N - 1 : ka);
    int kb = z0b / slab; kb = kb < 0 ? 0 : (kb > K_N - 1 ? K_N - 1 : kb);
    kka = ka < kb ? ka : kb;
    kkb = ka < kb ? kb : ka;
  }
  const int c_lo = (kka - 1) < 0 ? 0 : (kka - 1);
  const int c_hi = (kkb + 1) > (K_N - 1) ? (K_N - 1) : (kkb + 1);

  __shared__ ushort_t sKV[8192];       // 8KB K chunk || 8KB V chunk
  __shared__ ushort_t sP[4][16][72];   // per-wave single-tile P round-trip

  // Q A-fragments (2 tiles)
  bf16x8 aq[2][2];
  const int qrow0 = (b * DZ_N + z) * HW_N + p0 + th * 32;
#pragma unroll
  for (int t = 0; t < 2; t++) {
    const ushort_t* qp = &Qbf[(qrow0 + t * 16 + col) * E_N + h * 64 + quad * 8];
    aq[t][0] = *(const bf16x8*)qp;
    aq[t][1] = *(const bf16x8*)(qp + 32);
  }

  f32x4 oacc[2][4];
#pragma unroll
  for (int t = 0; t < 2; t++)
#pragma unroll
    for (int dt = 0; dt < 4; dt++) oacc[t][dt] = (f32x4){0.f, 0.f, 0.f, 0.f};
  float lsum[2][4] = {{0.f,0.f,0.f,0.f},{0.f,0.f,0.f,0.f}};

  // staging helper state: each thread stages 64 B (4 x uint4)
  const int sHalf = tid >> 7;              // 0 = K, 1 = V
  const int sOff = (tid & 127) * 32;       // shorts within 8KB chunk
  const ushort_t* sKbase = sKV;
  const ushort_t* sVbase = sKV + 4096;
  uint4* sDst = (uint4*)(sKV + sHalf * 4096 + sOff);

  auto cbase_of = [&](int c) {
    return (size_t)(((b * K_N + c) * 4 + h) * 9) * 4096;
  };

  uint4 stg[4];
  {  // prologue: prefetch chunk (c_lo, pc=0)
    const ushort_t* gsrc =
        (sHalf ? Vtp : Kpk) + cbase_of(c_lo) + 0 * 4096 + sOff;
#pragma unroll
    for (int j = 0; j < 4; j++) stg[j] = ((const uint4*)gsrc)[j];
  }

  for (int c = c_lo; c <= c_hi; c++) {
    const bool act = (c >= kkw - 1) && (c <= kkw + 1);
    const float biasE2 = ((c == kkw) ? -20.0f : -20.5f) * LOG2E;
    const float* topoc = &topo[(b * K_N + c) * HW_N + p0];
#pragma unroll 1
    for (int pc = 0; pc < 9; pc++) {
      __syncthreads();                    // all waves done reading prev chunk
#pragma unroll
      for (int j = 0; j < 4; j++) sDst[j] = stg[j];
      __syncthreads();                    // chunk visible to all waves
      // prefetch next chunk into regs (overlaps with compute below)
      {
        int pc2 = pc + 1, c2 = c;
        if (pc2 == 9) { pc2 = 0; c2 = c + 1; }
        if (c2 <= c_hi) {
          const ushort_t* gsrc =
              (sHalf ? Vtp : Kpk) + cbase_of(c2) + pc2 * 4096 + sOff;
#pragma unroll
          for (int j = 0; j < 4; j++) stg[j] = ((const uint4*)gsrc)[j];
        }
      }
      if (!act) continue;

      // ---- cache V B-frags (swizzled reads, conflict-free) ----
      bf16x8 bv[4][2];
#pragma unroll
      for (int dt = 0; dt < 4; dt++) {
        const int dr = dt * 16 + col;
        const int s7 = dr & 7;
        const ushort_t* vrow = sVbase + dr * 64;
        bv[dt][0] = *(const bf16x8*)(vrow + ((quad ^ s7) * 8));
        bv[dt][1] = *(const bf16x8*)(vrow + (((quad + 4) ^ s7) * 8));
      }

      const bool dflag = (pc == pb) && ((col >> 2) == quad);
#pragma unroll
      for (int t = 0; t < 2; t++) {
        // ---- QK ----
        f32x4 qk[4];
#pragma unroll
        for (int ct = 0; ct < 4; ct++) {
          const int kr = ct * 16 + col;
          const int s7 = kr & 7;
          const ushort_t* krow = sKbase + kr * 64;
          bf16x8 bk0 = *(const bf16x8*)(krow + ((quad ^ s7) * 8));
          bf16x8 bk1 = *(const bf16x8*)(krow + (((quad + 4) ^ s7) * 8));
          f32x4 acc = (f32x4){0.f, 0.f, 0.f, 0.f};
          acc = __builtin_amdgcn_mfma_f32_16x16x32_bf16(aq[t][0], bk0, acc, 0, 0, 0);
          acc = __builtin_amdgcn_mfma_f32_16x16x32_bf16(aq[t][1], bk1, acc, 0, 0, 0);
          qk[ct] = acc;
        }
        // ---- softmax (fixed-max, exp2) + permuted b64 P store ----
        const int ctt = th * 2 + t;
        const float tv2 = dflag ? lam2 * topoc[th * 32 + t * 16 + col] : 0.f;
#pragma unroll
        for (int r = 0; r < 4; r++) {
          float e[4];
#pragma unroll
          for (int ct = 0; ct < 4; ct++) {
            float x = fmaf(qk[ct][r], S2, biasE2);
            if (pc == pb && ct == ctt)
              x += ((col & 3) == r) ? tv2 : 0.f;
            e[ct] = __builtin_amdgcn_exp2f(x);
            lsum[t][r] += e[ct];
          }
          unsigned lo = (__float_as_uint(e[0]) >> 16) |
                        (__float_as_uint(e[1]) & 0xFFFF0000u);
          unsigned hi = (__float_as_uint(e[2]) >> 16) |
                        (__float_as_uint(e[3]) & 0xFFFF0000u);
          *(uint2*)&sP[w][quad * 4 + r][col * 4] = (uint2){lo, hi};
        }
        // ---- PV ----
        const bf16x8 ap0 = *(const bf16x8*)&sP[w][col][quad * 8];
        const bf16x8 ap1 = *(const bf16x8*)&sP[w][col][32 + quad * 8];
#pragma unroll
        for (int dt = 0; dt < 4; dt++) {
          oacc[t][dt] = __builtin_amdgcn_mfma_f32_16x16x32_bf16(ap0, bv[dt][0], oacc[t][dt], 0, 0, 0);
          oacc[t][dt] = __builtin_amdgcn_mfma_f32_16x16x32_bf16(ap1, bv[dt][1], oacc[t][dt], 0, 0, 0);
        }
      }
    }
  }

  // epilogue
#pragma unroll
  for (int t = 0; t < 2; t++)
#pragma unroll
    for (int r = 0; r < 4; r++) {
      float l = lsum[t][r];
      l += __shfl_xor(l, 1); l += __shfl_xor(l, 2);
      l += __shfl_xor(l, 4); l += __shfl_xor(l, 8);
      const float invl = 1.f / l;
      const int row = qrow0 + t * 16 + quad * 4 + r;
#pragma unroll
      for (int dt = 0; dt < 4; dt++)
        O[row * E_N + h * 64 + dt * 16 + col] = oacc[t][dt][r] * invl;
    }
}

// ---------------------------------------------------------------------------
// Output projection + residual (unchanged).
// ---------------------------------------------------------------------------
__global__ __launch_bounds__(256) void out_proj(
    const float* __restrict__ O, const float* __restrict__ Wp,
    const float* __restrict__ F3, float* __restrict__ outp) {
  __shared__ float sA[16][68];
  __shared__ float sW[16][128];
  __shared__ float sOut[64][129];
  const int tid = threadIdx.x;
  const int rowG = blockIdx.x * 64;
  float accv[8][4];
#pragma unroll
  for (int i = 0; i < 8; i++)
#pragma unroll
    for (int j = 0; j < 4; j++) accv[i][j] = 0.f;
  const int r0 = (tid >> 5) * 8;
  const int c0 = tid & 31;
  for (int k0 = 0; k0 < 256; k0 += 16) {
    if (k0) __syncthreads();
#pragma unroll
    for (int i = 0; i < 4; i++) {
      int idx = i * 256 + tid;
      int r = idx >> 4, kk = idx & 15;
      sA[kk][r] = O[(rowG + r) * E_N + k0 + kk];
    }
#pragma unroll
    for (int i = 0; i < 8; i++) {
      int idx = i * 256 + tid;
      int kk = idx >> 7, ccc = idx & 127;
      sW[kk][ccc] = Wp[(k0 + kk) * C3_N + ccc];
    }
    __syncthreads();
#pragma unroll 1
    for (int kk = 0; kk < 16; kk++) {
      float4 a0 = *(const float4*)&sA[kk][r0];
      float4 a1 = *(const float4*)&sA[kk][r0 + 4];
      float a[8] = {a0.x, a0.y, a0.z, a0.w, a1.x, a1.y, a1.z, a1.w};
#pragma unroll
      for (int j = 0; j < 4; j++) {
        float wv = sW[kk][c0 + 32 * j];
#pragma unroll
        for (int i = 0; i < 8; i++) accv[i][j] = fmaf(a[i], wv, accv[i][j]);
      }
    }
  }
  __syncthreads();
#pragma unroll
  for (int i = 0; i < 8; i++)
#pragma unroll
    for (int j = 0; j < 4; j++) sOut[r0 + i][c0 + 32 * j] = accv[i][j];
  __syncthreads();
  const int b = rowG / (DZ_N * HW_N);
  const int rem = rowG - b * DZ_N * HW_N;
  const int z = rem / HW_N;
  const int pp0 = rem - z * HW_N;
  const int pl = tid & 63, cg = tid >> 6;
  for (int cch = cg * 32; cch < cg * 32 + 32; cch++) {
    const int gidx = ((b * C3_N + cch) * DZ_N + z) * HW_N + pp0 + pl;
    outp[gidx] = F3[gidx] + sOut[pl][cch];
  }
}

// ---------------------------------------------------------------------------
extern "C" void kernel_launch(void* const* d_in, const int* in_sizes, int n_in,
                              void* d_out, int out_size, void* d_ws, size_t ws_size,
                              hipStream_t stream) {
  (void)in_sizes; (void)n_in; (void)out_size; (void)ws_size;
  const float* F3      = (const float*)d_in[0];
  const float* F2      = (const float*)d_in[1];
  const float* Wq      = (const float*)d_in[2];
  const float* Wk      = (const float*)d_in[3];
  const float* Wv      = (const float*)d_in[4];
  const float* Wp      = (const float*)d_in[5];
  const float* ln_q_g  = (const float*)d_in[6];
  const float* ln_q_b  = (const float*)d_in[7];
  const float* ln_kv_g = (const float*)d_in[8];
  const float* ln_kv_b = (const float*)d_in[9];
  const float* conv1_w = (const float*)d_in[10];
  const float* bn_g    = (const float*)d_in[11];
  const float* bn_b    = (const float*)d_in[12];
  const float* conv2_w = (const float*)d_in[13];
  const float* conv2_b = (const float*)d_in[14];
  const float* lam     = (const float*)d_in[15];
  const int*   D0      = (const int*)d_in[16];
  const int*   slab    = (const int*)d_in[17];
  float* out = (float*)d_out;

  char* ws = (char*)d_ws;
  size_t off = 0;
  auto alloc = [&](size_t bytes) {
    void* p = ws + off;
    off += (bytes + 255) & ~(size_t)255;
    return p;
  };
  const int QROWS = B_N * DZ_N * HW_N;   // 36864
  const int KVROWS = B_N * K_N * HW_N;   // 9216
  float* Qraw = (float*)alloc((size_t)QROWS * E_N * 4);   // -> reused as O
  float* Kraw = (float*)alloc((size_t)KVROWS * E_N * 4);  // Hp first
  float* Vraw = (float*)alloc((size_t)KVROWS * E_N * 4);  // -> Vtp
  ushort_t* Qbf = (ushort_t*)alloc((size_t)QROWS * E_N * 2);
  ushort_t* Kpk = (ushort_t*)alloc((size_t)KVROWS * E_N * 2);
  ushort_t* Vbf = (ushort_t*)alloc((size_t)KVROWS * E_N * 2);
  float* topo = (float*)alloc((size_t)B_N * K_N * HW_N * 4);
  float* Hp = Kraw;                    // dead before proj_gemm K runs
  ushort_t* Vtp = (ushort_t*)Vraw;     // Vraw dead after ln_bf16(V)
  float* O  = Qraw;                    // Qraw dead after ln_bf16(Q)

  // 1) topo branch
  topo_conv1<<<256, 384, 0, stream>>>(F2, conv1_w, Hp);
  topo_final<<<16, 576, 0, stream>>>(Hp, bn_g, bn_b, conv2_w, conv2_b, topo);
  // 2) projections (fp32); K/V col-split x2 for occupancy
  proj_gemm<128, 256><<<dim3(QROWS / 64, 1), 256, 0, stream>>>(
      F3, Wq, Qraw, DZ_N, C3_N * DZ_N * HW_N, HW_N, 1, DZ_N * HW_N);
  proj_gemm<96, 128><<<dim3(KVROWS / 64, 2), 256, 0, stream>>>(
      F2, Wk, Kraw, K_N, C2_N * HW_N * K_N, 1, K_N, HW_N * K_N);
  proj_gemm<96, 128><<<dim3(KVROWS / 64, 2), 256, 0, stream>>>(
      F2, Wv, Vraw, K_N, C2_N * HW_N * K_N, 1, K_N, HW_N * K_N);
  // 3) layernorm -> bf16 (K fused with swizzled packing)
  ln_bf16<<<QROWS / 4, 256, 0, stream>>>(Qraw, ln_q_g, ln_q_b, Qbf);
  ln_k_pack<<<KVROWS / 4, 256, 0, stream>>>(Kraw, ln_kv_g, ln_kv_b, Kpk);
  ln_bf16<<<KVROWS / 4, 256, 0, stream>>>(Vraw, ln_kv_g, ln_kv_b, Vbf);
  // 4) pack V^T (key-permuted + swizzled)
  pack_vt<<<B_N * K_N * 9, 256, 0, stream>>>(Vbf, Vtp);
  // 5) attention (LDS-staged, reg-prefetch pipelined)
  attn_kernel<<<1152, 256, 0, stream>>>(
      Qbf, Kpk, Vtp, topo, lam, D0, slab, O);
  // 6) output projection + residual
  out_proj<<<QROWS / 64, 256, 0, stream>>>(O, Wp, F3, out);
}

// Round 7
// 427.964 us; speedup vs baseline: 1.9497x; 1.1249x over previous
//
#include <hip/hip_runtime.h>

typedef float f32x4 __attribute__((ext_vector_type(4)));
typedef __bf16 bf16x8 __attribute__((ext_vector_type(8)));
typedef unsigned short ushort_t;

#define DEV_INLINE __device__ __forceinline__

constexpr int B_N  = 2;
constexpr int C3_N = 128;
constexpr int C2_N = 96;
constexpr int DZ_N = 32;
constexpr int H_N  = 24;
constexpr int W_N  = 24;
constexpr int K_N  = 8;
constexpr int E_N  = 256;
constexpr int HW_N = 576;

DEV_INLINE unsigned short f2bf(float x) {
  union { float f; unsigned u; } v; v.f = x;
  unsigned r = v.u + 0x7FFFu + ((v.u >> 16) & 1u);
  return (unsigned short)(r >> 16);
}

// ---------------------------------------------------------------------------
// Topo kernel A: partial 3x3 conv (C2->64), split over 4 c-chunks of 24.
// ---------------------------------------------------------------------------
__global__ __launch_bounds__(384) void topo_conv1(
    const float* __restrict__ F2, const float* __restrict__ W1,
    float* __restrict__ Hp) {
  const int bid = blockIdx.x;
  const int cc = bid & 3;
  const int tg = (bid >> 2) & 3;
  const int bk = bid >> 4;           // 0..15 = b*8 + k
  const int b = bk >> 3, k = bk & 7;
  const int tid = threadIdx.x;
  const int y = tid >> 4;            // 0..23
  const int tq = tid & 15;           // 0..15

  __shared__ float simg[8][26][28];
  __shared__ float sw[16 * 97];

  float acc[24];
#pragma unroll
  for (int i = 0; i < 24; i++) acc[i] = 0.f;

  float* simgf = &simg[0][0][0];
  for (int i = tid; i < 8 * 26 * 28; i += 384) simgf[i] = 0.f;
  __syncthreads();

  for (int ch = 0; ch < 3; ch++) {
    if (ch) __syncthreads();
    const int c0 = cc * 24 + ch * 8;
    for (int i = tid; i < 8 * 24 * 24; i += 384) {
      int c = i / 576, p = i - c * 576;
      int yy = p / 24, xx = p - yy * 24;
      simg[c][yy + 1][xx + 1] =
          F2[(((b * C2_N + c0 + c) * H_N + yy) * W_N + xx) * K_N + k];
    }
    for (int i = tid; i < 16 * 72; i += 384) {
      int t2 = i / 72, rest = i - t2 * 72;
      int c = rest / 9, q = rest - c * 9;
      sw[t2 * 97 + c * 12 + q] =
          W1[(tg * 16 + t2) * (C2_N * 9) + (c0 + c) * 9 + q];
    }
    __syncthreads();
#pragma unroll 1
    for (int c = 0; c < 8; c++) {
      float w[9];
#pragma unroll
      for (int q = 0; q < 9; q++) w[q] = sw[tq * 97 + c * 12 + q];
#pragma unroll
      for (int dy = 0; dy < 3; dy++) {
        float r[26];
#pragma unroll
        for (int xx = 0; xx < 26; xx++) r[xx] = simg[c][y + dy][xx];
#pragma unroll
        for (int dx = 0; dx < 3; dx++) {
          float wv = w[dy * 3 + dx];
#pragma unroll
          for (int xx = 0; xx < 24; xx++)
            acc[xx] = fmaf(wv, r[xx + dx], acc[xx]);
        }
      }
    }
  }
  const int t = tg * 16 + tq;
  float* dst = &Hp[((cc * 16 + bk) * 64 + t) * HW_N + y * 24];
#pragma unroll
  for (int xx = 0; xx < 24; xx++) dst[xx] = acc[xx];
}

// ---------------------------------------------------------------------------
// Topo kernel B: sum partials, bn+relu, 1x1 conv, neighbor sum.
// ---------------------------------------------------------------------------
__global__ __launch_bounds__(576) void topo_final(
    const float* __restrict__ Hp, const float* __restrict__ bn_g,
    const float* __restrict__ bn_b, const float* __restrict__ W2,
    const float* __restrict__ b2, float* __restrict__ topo) {
  const int bk = blockIdx.x;
  const int p = threadIdx.x;
  __shared__ float pp[26][28];
  float* ppf = &pp[0][0];
  for (int i = p; i < 26 * 28; i += 576) ppf[i] = 0.f;

  const float inv = rsqrtf(1.0f + 1e-5f);
  float acc = b2[0];
  for (int t = 0; t < 64; t++) {
    float v = 0.f;
#pragma unroll
    for (int c4 = 0; c4 < 4; c4++)
      v += Hp[((c4 * 16 + bk) * 64 + t) * HW_N + p];
    float hcv = fmaxf(fmaf(bn_g[t] * inv, v, bn_b[t]), 0.f);
    acc = fmaf(W2[t], hcv, acc);
  }
  __syncthreads();
  pp[p / 24 + 1][p % 24 + 1] = acc;
  __syncthreads();
  const int yy = p / 24 + 1, xx = p % 24 + 1;
  float s = pp[yy-1][xx-1] + pp[yy-1][xx] + pp[yy-1][xx+1]
          + pp[yy][xx-1]                  + pp[yy][xx+1]
          + pp[yy+1][xx-1] + pp[yy+1][xx] + pp[yy+1][xx+1];
  topo[bk * HW_N + p] = acc + 0.5f * s;
}

// ---------------------------------------------------------------------------
// Projection GEMM (fp32 vector), templated on COLS with col-split grid.y.
// ---------------------------------------------------------------------------
template <int CIN, int COLS>
__global__ __launch_bounds__(256) void proj_gemm(
    const float* __restrict__ src, const float* __restrict__ Wm,
    float* __restrict__ outp, int outer, int bStride, int oStride,
    int pStride, int cStride) {
  __shared__ float sA[16][64];
  __shared__ float sW[16][COLS];
  __shared__ int sRB[64];
  const int tid = threadIdx.x;
  const int cb = blockIdx.y * COLS;
  if (tid < 64) {
    int rr = blockIdx.x * 64 + tid;
    int bb = rr / (outer * HW_N);
    int rem = rr - bb * outer * HW_N;
    int o = rem / HW_N;
    int p = rem - o * HW_N;
    sRB[tid] = bb * bStride + o * oStride + p * pStride;
  }
  __syncthreads();
  constexpr int NJ = COLS / 32;
  float accv[8][NJ];
#pragma unroll
  for (int i = 0; i < 8; i++)
#pragma unroll
    for (int j = 0; j < NJ; j++) accv[i][j] = 0.f;
  const int r0 = (tid >> 5) * 8;
  const int c0 = tid & 31;
  for (int k0 = 0; k0 < CIN; k0 += 16) {
    if (k0) __syncthreads();
#pragma unroll
    for (int i = 0; i < 4; i++) {
      int idx = i * 256 + tid;
      int kk = idx >> 6, r = idx & 63;
      sA[kk][r] = src[sRB[r] + (k0 + kk) * cStride];
    }
#pragma unroll
    for (int i = 0; i < 16 * COLS / 256; i++) {
      int idx = i * 256 + tid;
      int kk = idx / COLS, ccc = idx % COLS;
      sW[kk][ccc] = Wm[(k0 + kk) * E_N + cb + ccc];
    }
    __syncthreads();
#pragma unroll 1
    for (int kk = 0; kk < 16; kk++) {
      float4 a0 = *(const float4*)&sA[kk][r0];
      float4 a1 = *(const float4*)&sA[kk][r0 + 4];
      float a[8] = {a0.x, a0.y, a0.z, a0.w, a1.x, a1.y, a1.z, a1.w};
#pragma unroll
      for (int j = 0; j < NJ; j++) {
        float wv = sW[kk][c0 + 32 * j];
#pragma unroll
        for (int i = 0; i < 8; i++) accv[i][j] = fmaf(a[i], wv, accv[i][j]);
      }
    }
  }
  const int rowG = blockIdx.x * 64;
#pragma unroll
  for (int i = 0; i < 8; i++)
#pragma unroll
    for (int j = 0; j < NJ; j++)
      outp[(rowG + r0 + i) * E_N + cb + c0 + 32 * j] = accv[i][j];
}

// ---------------------------------------------------------------------------
// LayerNorm over E=256, fp32 in -> bf16 out (row-major). One wave per row.
// ---------------------------------------------------------------------------
__global__ __launch_bounds__(256) void ln_bf16(
    const float* __restrict__ src, const float* __restrict__ g,
    const float* __restrict__ bb, ushort_t* __restrict__ dst) {
  const int w = threadIdx.x >> 6, lane = threadIdx.x & 63;
  const int row = blockIdx.x * 4 + w;
  const float4 x = *(const float4*)&src[row * E_N + lane * 4];
  float s = x.x + x.y + x.z + x.w;
#pragma unroll
  for (int off = 32; off; off >>= 1) s += __shfl_xor(s, off);
  const float mean = s * (1.f / 256.f);
  float4 d = {x.x - mean, x.y - mean, x.z - mean, x.w - mean};
  float v = d.x * d.x + d.y * d.y + d.z * d.z + d.w * d.w;
#pragma unroll
  for (int off = 32; off; off >>= 1) v += __shfl_xor(v, off);
  const float rstd = rsqrtf(v * (1.f / 256.f) + 1e-5f);
  const float4 gv = *(const float4*)&g[lane * 4];
  const float4 bv = *(const float4*)&bb[lane * 4];
  ushort4 o;
  o.x = f2bf(fmaf(d.x * rstd, gv.x, bv.x));
  o.y = f2bf(fmaf(d.y * rstd, gv.y, bv.y));
  o.z = f2bf(fmaf(d.z * rstd, gv.z, bv.z));
  o.w = f2bf(fmaf(d.w * rstd, gv.w, bv.w));
  *(ushort4*)&dst[row * E_N + lane * 4] = o;
}

// ---------------------------------------------------------------------------
// ln_k_pack: LayerNorm K rows AND scatter into per-(bk,h,pc) packed chunk
// [m][d] with 16B groups XOR-swizzled by (m&7) -> conflict-free LDS B-reads.
// ---------------------------------------------------------------------------
__global__ __launch_bounds__(256) void ln_k_pack(
    const float* __restrict__ src, const float* __restrict__ g,
    const float* __restrict__ bb, ushort_t* __restrict__ Kpk) {
  const int w = threadIdx.x >> 6, lane = threadIdx.x & 63;
  const int row = blockIdx.x * 4 + w;
  const float4 x = *(const float4*)&src[row * E_N + lane * 4];
  float s = x.x + x.y + x.z + x.w;
#pragma unroll
  for (int off = 32; off; off >>= 1) s += __shfl_xor(s, off);
  const float mean = s * (1.f / 256.f);
  float4 d = {x.x - mean, x.y - mean, x.z - mean, x.w - mean};
  float v = d.x * d.x + d.y * d.y + d.z * d.z + d.w * d.w;
#pragma unroll
  for (int off = 32; off; off >>= 1) v += __shfl_xor(v, off);
  const float rstd = rsqrtf(v * (1.f / 256.f) + 1e-5f);
  const float4 gv = *(const float4*)&g[lane * 4];
  const float4 bv = *(const float4*)&bb[lane * 4];
  ushort4 o;
  o.x = f2bf(fmaf(d.x * rstd, gv.x, bv.x));
  o.y = f2bf(fmaf(d.y * rstd, gv.y, bv.y));
  o.z = f2bf(fmaf(d.z * rstd, gv.z, bv.z));
  o.w = f2bf(fmaf(d.w * rstd, gv.w, bv.w));
  const int bk = row / HW_N;
  const int p = row - bk * HW_N;
  const int pc = p >> 6, m = p & 63;
  const int h = lane >> 4;
  const int dcol = (lane * 4) & 63;
  const int grp = (dcol >> 3) ^ (m & 7);           // XOR swizzle 16B groups
  const int idx = m * 64 + grp * 8 + (dcol & 7);
  ushort_t* dst = &Kpk[(((bk * 4 + h) * 9 + pc) * 4096) + idx];
  *(ushort4*)dst = o;
}

// ---------------------------------------------------------------------------
// pack_vt: Vbf -> per-(bk,h,pc) 8KB chunks [d][m'] with key dim PERMUTED
// m' = (m&15)*4 + (m>>4) (for b64 P-stores) AND 16B groups XOR-swizzled by
// (d&7) (for conflict-free LDS B-reads).
// ---------------------------------------------------------------------------
__global__ __launch_bounds__(256) void pack_vt(
    const ushort_t* __restrict__ Vbf, ushort_t* __restrict__ Vtp) {
  const int bid = blockIdx.x;
  const int pc = bid % 9;
  const int bk = bid / 9;
  const int tid = threadIdx.x;
  __shared__ ushort_t sT[64][264];
  {
    const int m = tid >> 2, jj = tid & 3;
    const int row = bk * HW_N + pc * 64 + m;
    const uint4* src = (const uint4*)&Vbf[row * E_N + jj * 64];
    uint4* d = (uint4*)&sT[m][jj * 64];
#pragma unroll
    for (int g = 0; g < 8; g++) d[g] = src[g];
  }
  __syncthreads();
  const int hh = tid >> 6, d = tid & 63;
  __attribute__((aligned(16))) ushort_t tmp[64];
#pragma unroll
  for (int j = 0; j < 64; j++)
    tmp[j] = sT[(j & 3) * 16 + (j >> 2)][hh * 64 + d];   // inverse perm gather
  const int chunk = (bk * 4 + hh) * 9 + pc;
  uint4* dst = (uint4*)&Vtp[chunk * 4096 + d * 64];
  const int sw = d & 7;
#pragma unroll
  for (int g = 0; g < 8; g++) dst[g ^ sw] = ((const uint4*)tmp)[g];
}

// ---------------------------------------------------------------------------
// Flash-style slab cross attention v7: LDS double-buffer filled by
// global_load_lds (async DMA, no VGPR round-trip, no LDS write instrs).
// grid 1152 = (hb 8 low: h,b) x (zp 16) x (pb 9); 256 thr = 4 waves.
// Wave w: z = 2*zp + (w>>1), 32 q-rows (2 tiles) at p0 + (w&1)*32.
// Pipeline: barrier (drains in-flight fill) -> issue fill(buf^1, next chunk)
// -> compute from buf. Fill latency hides behind ~500 cyc compute.
// ---------------------------------------------------------------------------
__global__ __launch_bounds__(256) void attn_kernel(
    const ushort_t* __restrict__ Qbf, const ushort_t* __restrict__ Kpk,
    const ushort_t* __restrict__ Vtp, const float* __restrict__ topo,
    const float* __restrict__ lamp, const int* __restrict__ D0p,
    const int* __restrict__ slabp, float* __restrict__ O) {
  const int bid = blockIdx.x;
  const int hb = bid & 7;
  const int h = hb & 3, b = hb >> 2;
  const int zp = (bid >> 3) & 15;
  const int pb = bid >> 7;                 // 0..8
  const int p0 = pb * 64;
  const int tid = threadIdx.x;
  const int w = tid >> 6, lane = tid & 63;
  const int quad = lane >> 4, col = lane & 15;
  const int z = zp * 2 + (w >> 1);
  const int th = w & 1;

  const float LOG2E = 1.44269504f;
  const float lam2 = lamp[0] * LOG2E;
  const float S2 = 0.125f * LOG2E;
  const int D0 = D0p[0], slab = slabp[0];
  const float step = (float)(D0 - 1) / (float)(DZ_N - 1);

  int kkw, kka, kkb;
  {
    int z0 = (int)floorf(fmaf((float)z, step, 0.5f));
    int kv = z0 / slab;
    kkw = kv < 0 ? 0 : (kv > K_N - 1 ? K_N - 1 : kv);
    int z0a = (int)floorf(fmaf((float)(zp * 2), step, 0.5f));
    int z0b = (int)floorf(fmaf((float)(zp * 2 + 1), step, 0.5f));
    int ka = z0a / slab; ka = ka < 0 ? 0 : (ka > K_N - 1 ? K_N - 1 : ka);
    int kb = z0b / slab; kb = kb < 0 ? 0 : (kb > K_N - 1 ? K_N - 1 : kb);
    kka = ka < kb ? ka : kb;
    kkb = ka < kb ? kb : ka;
  }
  const int c_lo = (kka - 1) < 0 ? 0 : (kka - 1);
  const int c_hi = (kkb + 1) > (K_N - 1) ? (K_N - 1) : (kkb + 1);

  __shared__ ushort_t sKV[2][8192];    // dbuf: [buf][ K 8KB | V 8KB ]
  __shared__ ushort_t sP[4][16][72];   // per-wave P round-trip

  // async fill: wave w DMAs 4 x 1KB segments (waves 0,1 -> K; 2,3 -> V)
  auto issue_fill = [&](int buf, int c, int pc) {
    const size_t cb = ((size_t)(((b * K_N + c) * 4 + h) * 9) + pc) * 4096;
#pragma unroll
    for (int j = 0; j < 4; j++) {
      const int seg = (w << 2) + j;    // 0..15
      const ushort_t* gsrc = (w < 2)
          ? (Kpk + cb + seg * 512 + lane * 8)
          : (Vtp + cb + (seg - 8) * 512 + lane * 8);
      ushort_t* ldst = &sKV[buf][seg * 512];  // wave-uniform; HW adds lane*16B
      __builtin_amdgcn_global_load_lds(
          (const __attribute__((address_space(1))) void*)gsrc,
          (__attribute__((address_space(3))) void*)ldst, 16, 0, 0);
    }
  };

  // Q A-fragments (2 tiles)
  bf16x8 aq[2][2];
  const int qrow0 = (b * DZ_N + z) * HW_N + p0 + th * 32;
#pragma unroll
  for (int t = 0; t < 2; t++) {
    const ushort_t* qp = &Qbf[(qrow0 + t * 16 + col) * E_N + h * 64 + quad * 8];
    aq[t][0] = *(const bf16x8*)qp;
    aq[t][1] = *(const bf16x8*)(qp + 32);
  }

  f32x4 oacc[2][4];
#pragma unroll
  for (int t = 0; t < 2; t++)
#pragma unroll
    for (int dt = 0; dt < 4; dt++) oacc[t][dt] = (f32x4){0.f, 0.f, 0.f, 0.f};
  float lsum[2][4] = {{0.f,0.f,0.f,0.f},{0.f,0.f,0.f,0.f}};

  int buf = 0;
  issue_fill(0, c_lo, 0);   // prologue

  for (int c = c_lo; c <= c_hi; c++) {
    const bool act = (c >= kkw - 1) && (c <= kkw + 1);
    const float biasE2 = ((c == kkw) ? -20.0f : -20.5f) * LOG2E;
    const float* topoc = &topo[(b * K_N + c) * HW_N + p0];
#pragma unroll 1
    for (int pc = 0; pc < 9; pc++) {
      __syncthreads();   // drains this wave's fill (vmcnt0) + all waves arrive
      {                  // issue next chunk's fill into the other buffer
        int pc2 = pc + 1, c2 = c;
        if (pc2 == 9) { pc2 = 0; c2 = c + 1; }
        if (c2 <= c_hi) issue_fill(buf ^ 1, c2, pc2);
      }
      const ushort_t* sKbase = &sKV[buf][0];
      const ushort_t* sVbase = &sKV[buf][4096];
      buf ^= 1;
      if (!act) continue;

      // ---- cache V B-frags (swizzled reads, conflict-free) ----
      bf16x8 bv[4][2];
#pragma unroll
      for (int dt = 0; dt < 4; dt++) {
        const int dr = dt * 16 + col;
        const int s7 = dr & 7;
        const ushort_t* vrow = sVbase + dr * 64;
        bv[dt][0] = *(const bf16x8*)(vrow + ((quad ^ s7) * 8));
        bv[dt][1] = *(const bf16x8*)(vrow + (((quad + 4) ^ s7) * 8));
      }

      const bool dflag = (pc == pb) && ((col >> 2) == quad);
#pragma unroll
      for (int t = 0; t < 2; t++) {
        // ---- QK ----
        f32x4 qk[4];
#pragma unroll
        for (int ct = 0; ct < 4; ct++) {
          const int kr = ct * 16 + col;
          const int s7 = kr & 7;
          const ushort_t* krow = sKbase + kr * 64;
          bf16x8 bk0 = *(const bf16x8*)(krow + ((quad ^ s7) * 8));
          bf16x8 bk1 = *(const bf16x8*)(krow + (((quad + 4) ^ s7) * 8));
          f32x4 acc = (f32x4){0.f, 0.f, 0.f, 0.f};
          acc = __builtin_amdgcn_mfma_f32_16x16x32_bf16(aq[t][0], bk0, acc, 0, 0, 0);
          acc = __builtin_amdgcn_mfma_f32_16x16x32_bf16(aq[t][1], bk1, acc, 0, 0, 0);
          qk[ct] = acc;
        }
        // ---- softmax (fixed-max, exp2) + permuted b64 P store ----
        const int ctt = th * 2 + t;
        const float tv2 = dflag ? lam2 * topoc[th * 32 + t * 16 + col] : 0.f;
#pragma unroll
        for (int r = 0; r < 4; r++) {
          float e[4];
#pragma unroll
          for (int ct = 0; ct < 4; ct++) {
            float x = fmaf(qk[ct][r], S2, biasE2);
            if (pc == pb && ct == ctt)
              x += ((col & 3) == r) ? tv2 : 0.f;
            e[ct] = __builtin_amdgcn_exp2f(x);
            lsum[t][r] += e[ct];
          }
          unsigned lo = (__float_as_uint(e[0]) >> 16) |
                        (__float_as_uint(e[1]) & 0xFFFF0000u);
          unsigned hi = (__float_as_uint(e[2]) >> 16) |
                        (__float_as_uint(e[3]) & 0xFFFF0000u);
          *(uint2*)&sP[w][quad * 4 + r][col * 4] = (uint2){lo, hi};
        }
        // ---- PV ----
        const bf16x8 ap0 = *(const bf16x8*)&sP[w][col][quad * 8];
        const bf16x8 ap1 = *(const bf16x8*)&sP[w][col][32 + quad * 8];
#pragma unroll
        for (int dt = 0; dt < 4; dt++) {
          oacc[t][dt] = __builtin_amdgcn_mfma_f32_16x16x32_bf16(ap0, bv[dt][0], oacc[t][dt], 0, 0, 0);
          oacc[t][dt] = __builtin_amdgcn_mfma_f32_16x16x32_bf16(ap1, bv[dt][1], oacc[t][dt], 0, 0, 0);
        }
      }
    }
  }

  // epilogue
#pragma unroll
  for (int t = 0; t < 2; t++)
#pragma unroll
    for (int r = 0; r < 4; r++) {
      float l = lsum[t][r];
      l += __shfl_xor(l, 1); l += __shfl_xor(l, 2);
      l += __shfl_xor(l, 4); l += __shfl_xor(l, 8);
      const float invl = 1.f / l;
      const int row = qrow0 + t * 16 + quad * 4 + r;
#pragma unroll
      for (int dt = 0; dt < 4; dt++)
        O[row * E_N + h * 64 + dt * 16 + col] = oacc[t][dt][r] * invl;
    }
}

// ---------------------------------------------------------------------------
// Output projection + residual (unchanged).
// ---------------------------------------------------------------------------
__global__ __launch_bounds__(256) void out_proj(
    const float* __restrict__ O, const float* __restrict__ Wp,
    const float* __restrict__ F3, float* __restrict__ outp) {
  __shared__ float sA[16][68];
  __shared__ float sW[16][128];
  __shared__ float sOut[64][129];
  const int tid = threadIdx.x;
  const int rowG = blockIdx.x * 64;
  float accv[8][4];
#pragma unroll
  for (int i = 0; i < 8; i++)
#pragma unroll
    for (int j = 0; j < 4; j++) accv[i][j] = 0.f;
  const int r0 = (tid >> 5) * 8;
  const int c0 = tid & 31;
  for (int k0 = 0; k0 < 256; k0 += 16) {
    if (k0) __syncthreads();
#pragma unroll
    for (int i = 0; i < 4; i++) {
      int idx = i * 256 + tid;
      int r = idx >> 4, kk = idx & 15;
      sA[kk][r] = O[(rowG + r) * E_N + k0 + kk];
    }
#pragma unroll
    for (int i = 0; i < 8; i++) {
      int idx = i * 256 + tid;
      int kk = idx >> 7, ccc = idx & 127;
      sW[kk][ccc] = Wp[(k0 + kk) * C3_N + ccc];
    }
    __syncthreads();
#pragma unroll 1
    for (int kk = 0; kk < 16; kk++) {
      float4 a0 = *(const float4*)&sA[kk][r0];
      float4 a1 = *(const float4*)&sA[kk][r0 + 4];
      float a[8] = {a0.x, a0.y, a0.z, a0.w, a1.x, a1.y, a1.z, a1.w};
#pragma unroll
      for (int j = 0; j < 4; j++) {
        float wv = sW[kk][c0 + 32 * j];
#pragma unroll
        for (int i = 0; i < 8; i++) accv[i][j] = fmaf(a[i], wv, accv[i][j]);
      }
    }
  }
  __syncthreads();
#pragma unroll
  for (int i = 0; i < 8; i++)
#pragma unroll
    for (int j = 0; j < 4; j++) sOut[r0 + i][c0 + 32 * j] = accv[i][j];
  __syncthreads();
  const int b = rowG / (DZ_N * HW_N);
  const int rem = rowG - b * DZ_N * HW_N;
  const int z = rem / HW_N;
  const int pp0 = rem - z * HW_N;
  const int pl = tid & 63, cg = tid >> 6;
  for (int cch = cg * 32; cch < cg * 32 + 32; cch++) {
    const int gidx = ((b * C3_N + cch) * DZ_N + z) * HW_N + pp0 + pl;
    outp[gidx] = F3[gidx] + sOut[pl][cch];
  }
}

// ---------------------------------------------------------------------------
extern "C" void kernel_launch(void* const* d_in, const int* in_sizes, int n_in,
                              void* d_out, int out_size, void* d_ws, size_t ws_size,
                              hipStream_t stream) {
  (void)in_sizes; (void)n_in; (void)out_size; (void)ws_size;
  const float* F3      = (const float*)d_in[0];
  const float* F2      = (const float*)d_in[1];
  const float* Wq      = (const float*)d_in[2];
  const float* Wk      = (const float*)d_in[3];
  const float* Wv      = (const float*)d_in[4];
  const float* Wp      = (const float*)d_in[5];
  const float* ln_q_g  = (const float*)d_in[6];
  const float* ln_q_b  = (const float*)d_in[7];
  const float* ln_kv_g = (const float*)d_in[8];
  const float* ln_kv_b = (const float*)d_in[9];
  const float* conv1_w = (const float*)d_in[10];
  const float* bn_g    = (const float*)d_in[11];
  const float* bn_b    = (const float*)d_in[12];
  const float* conv2_w = (const float*)d_in[13];
  const float* conv2_b = (const float*)d_in[14];
  const float* lam     = (const float*)d_in[15];
  const int*   D0      = (const int*)d_in[16];
  const int*   slab    = (const int*)d_in[17];
  float* out = (float*)d_out;

  char* ws = (char*)d_ws;
  size_t off = 0;
  auto alloc = [&](size_t bytes) {
    void* p = ws + off;
    off += (bytes + 255) & ~(size_t)255;
    return p;
  };
  const int QROWS = B_N * DZ_N * HW_N;   // 36864
  const int KVROWS = B_N * K_N * HW_N;   // 9216
  float* Qraw = (float*)alloc((size_t)QROWS * E_N * 4);   // -> reused as O
  float* Kraw = (float*)alloc((size_t)KVROWS * E_N * 4);  // Hp first
  float* Vraw = (float*)alloc((size_t)KVROWS * E_N * 4);  // -> Vtp
  ushort_t* Qbf = (ushort_t*)alloc((size_t)QROWS * E_N * 2);
  ushort_t* Kpk = (ushort_t*)alloc((size_t)KVROWS * E_N * 2);
  ushort_t* Vbf = (ushort_t*)alloc((size_t)KVROWS * E_N * 2);
  float* topo = (float*)alloc((size_t)B_N * K_N * HW_N * 4);
  float* Hp = Kraw;                    // dead before proj_gemm K runs
  ushort_t* Vtp = (ushort_t*)Vraw;     // Vraw dead after ln_bf16(V)
  float* O  = Qraw;                    // Qraw dead after ln_bf16(Q)

  // 1) topo branch
  topo_conv1<<<256, 384, 0, stream>>>(F2, conv1_w, Hp);
  topo_final<<<16, 576, 0, stream>>>(Hp, bn_g, bn_b, conv2_w, conv2_b, topo);
  // 2) projections (fp32); K/V col-split x2 for occupancy
  proj_gemm<128, 256><<<dim3(QROWS / 64, 1), 256, 0, stream>>>(
      F3, Wq, Qraw, DZ_N, C3_N * DZ_N * HW_N, HW_N, 1, DZ_N * HW_N);
  proj_gemm<96, 128><<<dim3(KVROWS / 64, 2), 256, 0, stream>>>(
      F2, Wk, Kraw, K_N, C2_N * HW_N * K_N, 1, K_N, HW_N * K_N);
  proj_gemm<96, 128><<<dim3(KVROWS / 64, 2), 256, 0, stream>>>(
      F2, Wv, Vraw, K_N, C2_N * HW_N * K_N, 1, K_N, HW_N * K_N);
  // 3) layernorm -> bf16 (K fused with swizzled packing)
  ln_bf16<<<QROWS / 4, 256, 0, stream>>>(Qraw, ln_q_g, ln_q_b, Qbf);
  ln_k_pack<<<KVROWS / 4, 256, 0, stream>>>(Kraw, ln_kv_g, ln_kv_b, Kpk);
  ln_bf16<<<KVROWS / 4, 256, 0, stream>>>(Vraw, ln_kv_g, ln_kv_b, Vbf);
  // 4) pack V^T (key-permuted + swizzled)
  pack_vt<<<B_N * K_N * 9, 256, 0, stream>>>(Vbf, Vtp);
  // 5) attention (global_load_lds double-buffered)
  attn_kernel<<<1152, 256, 0, stream>>>(
      Qbf, Kpk, Vtp, topo, lam, D0, slab, O);
  // 6) output projection + residual
  out_proj<<<QROWS / 64, 256, 0, stream>>>(O, Wp, F3, out);
}

// Round 8
// 385.508 us; speedup vs baseline: 2.1644x; 1.1101x over previous
//
#include <hip/hip_runtime.h>

typedef float f32x4 __attribute__((ext_vector_type(4)));
typedef __bf16 bf16x8 __attribute__((ext_vector_type(8)));
typedef unsigned short ushort_t;

#define DEV_INLINE __device__ __forceinline__

constexpr int B_N  = 2;
constexpr int C3_N = 128;
constexpr int C2_N = 96;
constexpr int DZ_N = 32;
constexpr int H_N  = 24;
constexpr int W_N  = 24;
constexpr int K_N  = 8;
constexpr int E_N  = 256;
constexpr int HW_N = 576;

DEV_INLINE unsigned short f2bf(float x) {
  union { float f; unsigned u; } v; v.f = x;
  unsigned r = v.u + 0x7FFFu + ((v.u >> 16) & 1u);
  return (unsigned short)(r >> 16);
}

// ---------------------------------------------------------------------------
// Topo kernel A: partial 3x3 conv (C2->64), split over 4 c-chunks of 24.
// ---------------------------------------------------------------------------
__global__ __launch_bounds__(384) void topo_conv1(
    const float* __restrict__ F2, const float* __restrict__ W1,
    float* __restrict__ Hp) {
  const int bid = blockIdx.x;
  const int cc = bid & 3;
  const int tg = (bid >> 2) & 3;
  const int bk = bid >> 4;           // 0..15 = b*8 + k
  const int b = bk >> 3, k = bk & 7;
  const int tid = threadIdx.x;
  const int y = tid >> 4;            // 0..23
  const int tq = tid & 15;           // 0..15

  __shared__ float simg[8][26][28];
  __shared__ float sw[16 * 97];

  float acc[24];
#pragma unroll
  for (int i = 0; i < 24; i++) acc[i] = 0.f;

  float* simgf = &simg[0][0][0];
  for (int i = tid; i < 8 * 26 * 28; i += 384) simgf[i] = 0.f;
  __syncthreads();

  for (int ch = 0; ch < 3; ch++) {
    if (ch) __syncthreads();
    const int c0 = cc * 24 + ch * 8;
    for (int i = tid; i < 8 * 24 * 24; i += 384) {
      int c = i / 576, p = i - c * 576;
      int yy = p / 24, xx = p - yy * 24;
      simg[c][yy + 1][xx + 1] =
          F2[(((b * C2_N + c0 + c) * H_N + yy) * W_N + xx) * K_N + k];
    }
    for (int i = tid; i < 16 * 72; i += 384) {
      int t2 = i / 72, rest = i - t2 * 72;
      int c = rest / 9, q = rest - c * 9;
      sw[t2 * 97 + c * 12 + q] =
          W1[(tg * 16 + t2) * (C2_N * 9) + (c0 + c) * 9 + q];
    }
    __syncthreads();
#pragma unroll 1
    for (int c = 0; c < 8; c++) {
      float w[9];
#pragma unroll
      for (int q = 0; q < 9; q++) w[q] = sw[tq * 97 + c * 12 + q];
#pragma unroll
      for (int dy = 0; dy < 3; dy++) {
        float r[26];
#pragma unroll
        for (int xx = 0; xx < 26; xx++) r[xx] = simg[c][y + dy][xx];
#pragma unroll
        for (int dx = 0; dx < 3; dx++) {
          float wv = w[dy * 3 + dx];
#pragma unroll
          for (int xx = 0; xx < 24; xx++)
            acc[xx] = fmaf(wv, r[xx + dx], acc[xx]);
        }
      }
    }
  }
  const int t = tg * 16 + tq;
  float* dst = &Hp[((cc * 16 + bk) * 64 + t) * HW_N + y * 24];
#pragma unroll
  for (int xx = 0; xx < 24; xx++) dst[xx] = acc[xx];
}

// ---------------------------------------------------------------------------
// Topo B1: per-(bk, t-group) partial bn+relu+1x1 reduction. 64 blocks.
// ---------------------------------------------------------------------------
__global__ __launch_bounds__(576) void topo_mid(
    const float* __restrict__ Hp, const float* __restrict__ bn_g,
    const float* __restrict__ bn_b, const float* __restrict__ W2,
    float* __restrict__ part) {
  const int bid = blockIdx.x;
  const int tg = bid & 3, bk = bid >> 2;
  const int p = threadIdx.x;
  const float inv = rsqrtf(1.0f + 1e-5f);
  float acc = 0.f;
#pragma unroll 1
  for (int tt = 0; tt < 16; tt++) {
    const int t = tg * 16 + tt;
    float v = 0.f;
#pragma unroll
    for (int c4 = 0; c4 < 4; c4++)
      v += Hp[((c4 * 16 + bk) * 64 + t) * HW_N + p];
    acc = fmaf(W2[t], fmaxf(fmaf(bn_g[t] * inv, v, bn_b[t]), 0.f), acc);
  }
  part[(bk * 4 + tg) * HW_N + p] = acc;
}

// ---------------------------------------------------------------------------
// Topo B2: combine partials + neighbor halo sum. 16 blocks.
// ---------------------------------------------------------------------------
__global__ __launch_bounds__(576) void topo_final2(
    const float* __restrict__ part, const float* __restrict__ b2,
    float* __restrict__ topo) {
  const int bk = blockIdx.x;
  const int p = threadIdx.x;
  __shared__ float pp[26][28];
  float* ppf = &pp[0][0];
  for (int i = p; i < 26 * 28; i += 576) ppf[i] = 0.f;
  float acc = b2[0];
#pragma unroll
  for (int tg = 0; tg < 4; tg++) acc += part[(bk * 4 + tg) * HW_N + p];
  __syncthreads();
  pp[p / 24 + 1][p % 24 + 1] = acc;
  __syncthreads();
  const int yy = p / 24 + 1, xx = p % 24 + 1;
  float s = pp[yy-1][xx-1] + pp[yy-1][xx] + pp[yy-1][xx+1]
          + pp[yy][xx-1]                  + pp[yy][xx+1]
          + pp[yy+1][xx-1] + pp[yy+1][xx] + pp[yy+1][xx+1];
  topo[bk * HW_N + p] = acc + 0.5f * s;
}

// ---------------------------------------------------------------------------
// Projection GEMM (fp32 vector), templated on COLS with col-split grid.y.
// ---------------------------------------------------------------------------
template <int CIN, int COLS>
__global__ __launch_bounds__(256) void proj_gemm(
    const float* __restrict__ src, const float* __restrict__ Wm,
    float* __restrict__ outp, int outer, int bStride, int oStride,
    int pStride, int cStride) {
  __shared__ float sA[16][64];
  __shared__ float sW[16][COLS];
  __shared__ int sRB[64];
  const int tid = threadIdx.x;
  const int cb = blockIdx.y * COLS;
  if (tid < 64) {
    int rr = blockIdx.x * 64 + tid;
    int bb = rr / (outer * HW_N);
    int rem = rr - bb * outer * HW_N;
    int o = rem / HW_N;
    int p = rem - o * HW_N;
    sRB[tid] = bb * bStride + o * oStride + p * pStride;
  }
  __syncthreads();
  constexpr int NJ = COLS / 32;
  float accv[8][NJ];
#pragma unroll
  for (int i = 0; i < 8; i++)
#pragma unroll
    for (int j = 0; j < NJ; j++) accv[i][j] = 0.f;
  const int r0 = (tid >> 5) * 8;
  const int c0 = tid & 31;
  for (int k0 = 0; k0 < CIN; k0 += 16) {
    if (k0) __syncthreads();
#pragma unroll
    for (int i = 0; i < 4; i++) {
      int idx = i * 256 + tid;
      int kk = idx >> 6, r = idx & 63;
      sA[kk][r] = src[sRB[r] + (k0 + kk) * cStride];
    }
#pragma unroll
    for (int i = 0; i < 16 * COLS / 256; i++) {
      int idx = i * 256 + tid;
      int kk = idx / COLS, ccc = idx % COLS;
      sW[kk][ccc] = Wm[(k0 + kk) * E_N + cb + ccc];
    }
    __syncthreads();
#pragma unroll 1
    for (int kk = 0; kk < 16; kk++) {
      float4 a0 = *(const float4*)&sA[kk][r0];
      float4 a1 = *(const float4*)&sA[kk][r0 + 4];
      float a[8] = {a0.x, a0.y, a0.z, a0.w, a1.x, a1.y, a1.z, a1.w};
#pragma unroll
      for (int j = 0; j < NJ; j++) {
        float wv = sW[kk][c0 + 32 * j];
#pragma unroll
        for (int i = 0; i < 8; i++) accv[i][j] = fmaf(a[i], wv, accv[i][j]);
      }
    }
  }
  const int rowG = blockIdx.x * 64;
#pragma unroll
  for (int i = 0; i < 8; i++)
#pragma unroll
    for (int j = 0; j < NJ; j++)
      outp[(rowG + r0 + i) * E_N + cb + c0 + 32 * j] = accv[i][j];
}

// ---------------------------------------------------------------------------
// LayerNorm over E=256, fp32 in -> bf16 out (row-major). One wave per row.
// ---------------------------------------------------------------------------
__global__ __launch_bounds__(256) void ln_bf16(
    const float* __restrict__ src, const float* __restrict__ g,
    const float* __restrict__ bb, ushort_t* __restrict__ dst) {
  const int w = threadIdx.x >> 6, lane = threadIdx.x & 63;
  const int row = blockIdx.x * 4 + w;
  const float4 x = *(const float4*)&src[row * E_N + lane * 4];
  float s = x.x + x.y + x.z + x.w;
#pragma unroll
  for (int off = 32; off; off >>= 1) s += __shfl_xor(s, off);
  const float mean = s * (1.f / 256.f);
  float4 d = {x.x - mean, x.y - mean, x.z - mean, x.w - mean};
  float v = d.x * d.x + d.y * d.y + d.z * d.z + d.w * d.w;
#pragma unroll
  for (int off = 32; off; off >>= 1) v += __shfl_xor(v, off);
  const float rstd = rsqrtf(v * (1.f / 256.f) + 1e-5f);
  const float4 gv = *(const float4*)&g[lane * 4];
  const float4 bv = *(const float4*)&bb[lane * 4];
  ushort4 o;
  o.x = f2bf(fmaf(d.x * rstd, gv.x, bv.x));
  o.y = f2bf(fmaf(d.y * rstd, gv.y, bv.y));
  o.z = f2bf(fmaf(d.z * rstd, gv.z, bv.z));
  o.w = f2bf(fmaf(d.w * rstd, gv.w, bv.w));
  *(ushort4*)&dst[row * E_N + lane * 4] = o;
}

// ---------------------------------------------------------------------------
// ln_k_pack: LayerNorm K rows AND scatter into per-(bk,h,pc) packed chunk
// [m][d] with 16B groups XOR-swizzled by (m&7) -> conflict-free LDS A-reads.
// ---------------------------------------------------------------------------
__global__ __launch_bounds__(256) void ln_k_pack(
    const float* __restrict__ src, const float* __restrict__ g,
    const float* __restrict__ bb, ushort_t* __restrict__ Kpk) {
  const int w = threadIdx.x >> 6, lane = threadIdx.x & 63;
  const int row = blockIdx.x * 4 + w;
  const float4 x = *(const float4*)&src[row * E_N + lane * 4];
  float s = x.x + x.y + x.z + x.w;
#pragma unroll
  for (int off = 32; off; off >>= 1) s += __shfl_xor(s, off);
  const float mean = s * (1.f / 256.f);
  float4 d = {x.x - mean, x.y - mean, x.z - mean, x.w - mean};
  float v = d.x * d.x + d.y * d.y + d.z * d.z + d.w * d.w;
#pragma unroll
  for (int off = 32; off; off >>= 1) v += __shfl_xor(v, off);
  const float rstd = rsqrtf(v * (1.f / 256.f) + 1e-5f);
  const float4 gv = *(const float4*)&g[lane * 4];
  const float4 bv = *(const float4*)&bb[lane * 4];
  ushort4 o;
  o.x = f2bf(fmaf(d.x * rstd, gv.x, bv.x));
  o.y = f2bf(fmaf(d.y * rstd, gv.y, bv.y));
  o.z = f2bf(fmaf(d.z * rstd, gv.z, bv.z));
  o.w = f2bf(fmaf(d.w * rstd, gv.w, bv.w));
  const int bk = row / HW_N;
  const int p = row - bk * HW_N;
  const int pc = p >> 6, m = p & 63;
  const int h = lane >> 4;
  const int dcol = (lane * 4) & 63;
  const int grp = (dcol >> 3) ^ (m & 7);           // XOR swizzle 16B groups
  const int idx = m * 64 + grp * 8 + (dcol & 7);
  ushort_t* dst = &Kpk[(((bk * 4 + h) * 9 + pc) * 4096) + idx];
  *(ushort4*)dst = o;
}

// ---------------------------------------------------------------------------
// pack_vt_ln: fused LayerNorm(V) + transpose-pack. Per-(bk,h,pc) 8KB chunks
// [d][k] where position k holds key pi(k) = (k&32)+((k&4)<<2)+((k&24)>>1)+(k&3)
// (matches the attn in-register P B-frag order), 16B groups XOR-swizzled by
// (d&7). Thread (m=tid>>2, jj=tid&3) LNs one quarter-row.
// ---------------------------------------------------------------------------
__global__ __launch_bounds__(256) void pack_vt_ln(
    const float* __restrict__ Vraw, const float* __restrict__ g,
    const float* __restrict__ bb, ushort_t* __restrict__ Vtp) {
  const int bid = blockIdx.x;
  const int pc = bid % 9;
  const int bk = bid / 9;
  const int tid = threadIdx.x;
  __shared__ ushort_t sT[64][264];
  {
    const int m = tid >> 2, jj = tid & 3;
    const int row = bk * HW_N + pc * 64 + m;
    const float* src = &Vraw[row * E_N + jj * 64];
    float4 xv[16];
    float s = 0.f;
#pragma unroll
    for (int i = 0; i < 16; i++) {
      xv[i] = *(const float4*)&src[i * 4];
      s += xv[i].x + xv[i].y + xv[i].z + xv[i].w;
    }
    s += __shfl_xor(s, 1); s += __shfl_xor(s, 2);
    const float mean = s * (1.f / 256.f);
    float v = 0.f;
#pragma unroll
    for (int i = 0; i < 16; i++) {
      xv[i].x -= mean; xv[i].y -= mean; xv[i].z -= mean; xv[i].w -= mean;
      v += xv[i].x * xv[i].x + xv[i].y * xv[i].y +
           xv[i].z * xv[i].z + xv[i].w * xv[i].w;
    }
    v += __shfl_xor(v, 1); v += __shfl_xor(v, 2);
    const float rstd = rsqrtf(v * (1.f / 256.f) + 1e-5f);
    ushort_t* drow = &sT[m][jj * 64];
#pragma unroll
    for (int i = 0; i < 16; i++) {
      const float4 gv = *(const float4*)&g[jj * 64 + i * 4];
      const float4 bv = *(const float4*)&bb[jj * 64 + i * 4];
      ushort4 o;
      o.x = f2bf(fmaf(xv[i].x * rstd, gv.x, bv.x));
      o.y = f2bf(fmaf(xv[i].y * rstd, gv.y, bv.y));
      o.z = f2bf(fmaf(xv[i].z * rstd, gv.z, bv.z));
      o.w = f2bf(fmaf(xv[i].w * rstd, gv.w, bv.w));
      *(ushort4*)&drow[i * 4] = o;
    }
  }
  __syncthreads();
  const int hh = tid >> 6, d = tid & 63;
  __attribute__((aligned(16))) ushort_t tmp[64];
#pragma unroll
  for (int k = 0; k < 64; k++) {
    const int pk = (k & 32) + ((k & 4) << 2) + ((k & 24) >> 1) + (k & 3);
    tmp[k] = sT[pk][hh * 64 + d];
  }
  const int chunk = (bk * 4 + hh) * 9 + pc;
  uint4* dst = (uint4*)&Vtp[chunk * 4096 + d * 64];
  const int sw = d & 7;
#pragma unroll
  for (int gg = 0; gg < 8; gg++) dst[gg ^ sw] = ((const uint4*)tmp)[gg];
}

// ---------------------------------------------------------------------------
// Flash-style slab cross attention v8: transposed dataflow — S^T = K x Q^T,
// O^T = V^T x P^T. P stays IN REGISTERS (no LDS round-trip): the S^T C-layout
// per lane IS the PV B-frag under the pi key-permutation baked into Vtp.
// grid 1152 = (hb 8: h,b) x (zp 16) x (pb 9); 4 waves; wave = 2 q-tiles of
// one z. K/V chunks double-buffered via global_load_lds (32 KB LDS total).
// ---------------------------------------------------------------------------
__global__ __launch_bounds__(256) void attn_kernel(
    const ushort_t* __restrict__ Qbf, const ushort_t* __restrict__ Kpk,
    const ushort_t* __restrict__ Vtp, const float* __restrict__ topo,
    const float* __restrict__ lamp, const int* __restrict__ D0p,
    const int* __restrict__ slabp, float* __restrict__ O) {
  const int bid = blockIdx.x;
  const int hb = bid & 7;
  const int h = hb & 3, b = hb >> 2;
  const int zp = (bid >> 3) & 15;
  const int pb = bid >> 7;                 // 0..8
  const int p0 = pb * 64;
  const int tid = threadIdx.x;
  const int w = tid >> 6, lane = tid & 63;
  const int quad = lane >> 4, col = lane & 15;
  const int z = zp * 2 + (w >> 1);
  const int th = w & 1;

  const float LOG2E = 1.44269504f;
  const float lam2 = lamp[0] * LOG2E;
  const float S2 = 0.125f * LOG2E;
  const int D0 = D0p[0], slab = slabp[0];
  const float step = (float)(D0 - 1) / (float)(DZ_N - 1);

  int kkw, kka, kkb;
  {
    int z0 = (int)floorf(fmaf((float)z, step, 0.5f));
    int kv = z0 / slab;
    kkw = kv < 0 ? 0 : (kv > K_N - 1 ? K_N - 1 : kv);
    int z0a = (int)floorf(fmaf((float)(zp * 2), step, 0.5f));
    int z0b = (int)floorf(fmaf((float)(zp * 2 + 1), step, 0.5f));
    int ka = z0a / slab; ka = ka < 0 ? 0 : (ka > K_N - 1 ? K_N - 1 : ka);
    int kb = z0b / slab; kb = kb < 0 ? 0 : (kb > K_N - 1 ? K_N - 1 : kb);
    kka = ka < kb ? ka : kb;
    kkb = ka < kb ? kb : ka;
  }
  const int c_lo = (kka - 1) < 0 ? 0 : (kka - 1);
  const int c_hi = (kkb + 1) > (K_N - 1) ? (K_N - 1) : (kkb + 1);

  __shared__ ushort_t sKV[2][8192];    // dbuf: [buf][ K 8KB | V 8KB ] = 32 KB

  auto issue_fill = [&](int buf, int c, int pc) {
    const size_t cb = ((size_t)(((b * K_N + c) * 4 + h) * 9) + pc) * 4096;
#pragma unroll
    for (int j = 0; j < 4; j++) {
      const int seg = (w << 2) + j;    // 0..15
      const ushort_t* gsrc = (w < 2)
          ? (Kpk + cb + seg * 512 + lane * 8)
          : (Vtp + cb + (seg - 8) * 512 + lane * 8);
      ushort_t* ldst = &sKV[buf][seg * 512];
      __builtin_amdgcn_global_load_lds(
          (const __attribute__((address_space(1))) void*)gsrc,
          (__attribute__((address_space(3))) void*)ldst, 16, 0, 0);
    }
  };

  // Q B-frags (2 tiles): lane (quad,col) holds Q[q=col][dk=quad*8+j]
  bf16x8 bq[2][2];
  const int qrow0 = (b * DZ_N + z) * HW_N + p0 + th * 32;
#pragma unroll
  for (int t = 0; t < 2; t++) {
    const ushort_t* qp = &Qbf[(qrow0 + t * 16 + col) * E_N + h * 64 + quad * 8];
    bq[t][0] = *(const bf16x8*)qp;
    bq[t][1] = *(const bf16x8*)(qp + 32);
  }

  f32x4 oacc[2][4];
#pragma unroll
  for (int t = 0; t < 2; t++)
#pragma unroll
    for (int dt = 0; dt < 4; dt++) oacc[t][dt] = (f32x4){0.f, 0.f, 0.f, 0.f};
  float lsum[2] = {0.f, 0.f};

  const int s7 = col & 7;
  const int o1 = (quad ^ s7) * 8;
  const int o2 = ((quad + 4) ^ s7) * 8;

  int buf = 0;
  issue_fill(0, c_lo, 0);   // prologue

  for (int c = c_lo; c <= c_hi; c++) {
    const bool act = (c >= kkw - 1) && (c <= kkw + 1);
    const float biasE2 = ((c == kkw) ? -20.0f : -20.5f) * LOG2E;
    const float* topoc = &topo[(b * K_N + c) * HW_N + p0];
#pragma unroll 1
    for (int pc = 0; pc < 9; pc++) {
      __syncthreads();   // drains in-flight fill; all waves arrive
      {
        int pc2 = pc + 1, c2 = c;
        if (pc2 == 9) { pc2 = 0; c2 = c + 1; }
        if (c2 <= c_hi) issue_fill(buf ^ 1, c2, pc2);
      }
      const ushort_t* sKb = &sKV[buf][0];
      const ushort_t* sVb = &sKV[buf][4096];
      buf ^= 1;
      if (!act) continue;

      // K A-frags (t-invariant): lane holds K[key=kt*16+col][dk=quad*8+j]
      bf16x8 ka[4][2];
#pragma unroll
      for (int kt = 0; kt < 4; kt++) {
        const ushort_t* kr = sKb + (kt * 16 + col) * 64;
        ka[kt][0] = *(const bf16x8*)(kr + o1);
        ka[kt][1] = *(const bf16x8*)(kr + o2);
      }

      bf16x8 pfrag[2][2];
#pragma unroll
      for (int t = 0; t < 2; t++) {
        // S^T: lane reg r = S[q=col][key=kt*16+quad*4+r]
        f32x4 sv[4];
#pragma unroll
        for (int kt = 0; kt < 4; kt++) {
          f32x4 acc = (f32x4){0.f, 0.f, 0.f, 0.f};
          acc = __builtin_amdgcn_mfma_f32_16x16x32_bf16(ka[kt][0], bq[t][0], acc, 0, 0, 0);
          acc = __builtin_amdgcn_mfma_f32_16x16x32_bf16(ka[kt][1], bq[t][1], acc, 0, 0, 0);
          sv[kt] = acc;
        }
        float xv[4][4];
#pragma unroll
        for (int kt = 0; kt < 4; kt++)
#pragma unroll
          for (int r = 0; r < 4; r++)
            xv[kt][r] = fmaf(sv[kt][r], S2, biasE2);
        if (pc == pb) {   // wave-uniform branch: diag fixup only 1/9 chunks
          const int ctt = th * 2 + t;
          const float tv2 = lam2 * topoc[th * 32 + t * 16 + col];
          const bool qok = ((col >> 2) == quad);
#pragma unroll
          for (int kt = 0; kt < 4; kt++)
#pragma unroll
            for (int r = 0; r < 4; r++)
              xv[kt][r] += (qok && kt == ctt && (col & 3) == r) ? tv2 : 0.f;
        }
        float ev[4][4];
        float ls = 0.f;
#pragma unroll
        for (int kt = 0; kt < 4; kt++)
#pragma unroll
          for (int r = 0; r < 4; r++) {
            ev[kt][r] = __builtin_amdgcn_exp2f(xv[kt][r]);
            ls += ev[kt][r];
          }
        lsum[t] += ls;
        // pack P into PV B-frags in-register (pi order; truncate to bf16)
#pragma unroll
        for (int f = 0; f < 2; f++) {
          union { uint4 u; bf16x8 v; } pk;
          pk.u.x = __builtin_amdgcn_perm(__float_as_uint(ev[f*2][1]),
                                         __float_as_uint(ev[f*2][0]), 0x07060302u);
          pk.u.y = __builtin_amdgcn_perm(__float_as_uint(ev[f*2][3]),
                                         __float_as_uint(ev[f*2][2]), 0x07060302u);
          pk.u.z = __builtin_amdgcn_perm(__float_as_uint(ev[f*2+1][1]),
                                         __float_as_uint(ev[f*2+1][0]), 0x07060302u);
          pk.u.w = __builtin_amdgcn_perm(__float_as_uint(ev[f*2+1][3]),
                                         __float_as_uint(ev[f*2+1][2]), 0x07060302u);
          pfrag[t][f] = pk.v;
        }
      }

      // O^T += V^T x P^T: A = Vt rows (pi-packed keys), B = pfrag
#pragma unroll
      for (int dt = 0; dt < 4; dt++) {
        const ushort_t* vr = sVb + (dt * 16 + col) * 64;
        bf16x8 va0 = *(const bf16x8*)(vr + o1);
        bf16x8 va1 = *(const bf16x8*)(vr + o2);
#pragma unroll
        for (int t = 0; t < 2; t++) {
          oacc[t][dt] = __builtin_amdgcn_mfma_f32_16x16x32_bf16(va0, pfrag[t][0], oacc[t][dt], 0, 0, 0);
          oacc[t][dt] = __builtin_amdgcn_mfma_f32_16x16x32_bf16(va1, pfrag[t][1], oacc[t][dt], 0, 0, 0);
        }
      }
    }
  }

  // epilogue: l = reduce lsum over the 4 quad-lanes of this q (=col)
#pragma unroll
  for (int t = 0; t < 2; t++) {
    float l = lsum[t];
    l += __shfl_xor(l, 16);
    l += __shfl_xor(l, 32);
    const float invl = 1.f / l;
    const int row = qrow0 + t * 16 + col;
    float* orow = &O[row * E_N + h * 64];
#pragma unroll
    for (int dt = 0; dt < 4; dt++) {
      f32x4 ov = oacc[t][dt];
      ov[0] *= invl; ov[1] *= invl; ov[2] *= invl; ov[3] *= invl;
      *(f32x4*)&orow[dt * 16 + quad * 4] = ov;
    }
  }
}

// ---------------------------------------------------------------------------
// Output projection + residual (unchanged).
// ---------------------------------------------------------------------------
__global__ __launch_bounds__(256) void out_proj(
    const float* __restrict__ O, const float* __restrict__ Wp,
    const float* __restrict__ F3, float* __restrict__ outp) {
  __shared__ float sA[16][68];
  __shared__ float sW[16][128];
  __shared__ float sOut[64][129];
  const int tid = threadIdx.x;
  const int rowG = blockIdx.x * 64;
  float accv[8][4];
#pragma unroll
  for (int i = 0; i < 8; i++)
#pragma unroll
    for (int j = 0; j < 4; j++) accv[i][j] = 0.f;
  const int r0 = (tid >> 5) * 8;
  const int c0 = tid & 31;
  for (int k0 = 0; k0 < 256; k0 += 16) {
    if (k0) __syncthreads();
#pragma unroll
    for (int i = 0; i < 4; i++) {
      int idx = i * 256 + tid;
      int r = idx >> 4, kk = idx & 15;
      sA[kk][r] = O[(rowG + r) * E_N + k0 + kk];
    }
#pragma unroll
    for (int i = 0; i < 8; i++) {
      int idx = i * 256 + tid;
      int kk = idx >> 7, ccc = idx & 127;
      sW[kk][ccc] = Wp[(k0 + kk) * C3_N + ccc];
    }
    __syncthreads();
#pragma unroll 1
    for (int kk = 0; kk < 16; kk++) {
      float4 a0 = *(const float4*)&sA[kk][r0];
      float4 a1 = *(const float4*)&sA[kk][r0 + 4];
      float a[8] = {a0.x, a0.y, a0.z, a0.w, a1.x, a1.y, a1.z, a1.w};
#pragma unroll
      for (int j = 0; j < 4; j++) {
        float wv = sW[kk][c0 + 32 * j];
#pragma unroll
        for (int i = 0; i < 8; i++) accv[i][j] = fmaf(a[i], wv, accv[i][j]);
      }
    }
  }
  __syncthreads();
#pragma unroll
  for (int i = 0; i < 8; i++)
#pragma unroll
    for (int j = 0; j < 4; j++) sOut[r0 + i][c0 + 32 * j] = accv[i][j];
  __syncthreads();
  const int b = rowG / (DZ_N * HW_N);
  const int rem = rowG - b * DZ_N * HW_N;
  const int z = rem / HW_N;
  const int pp0 = rem - z * HW_N;
  const int pl = tid & 63, cg = tid >> 6;
  for (int cch = cg * 32; cch < cg * 32 + 32; cch++) {
    const int gidx = ((b * C3_N + cch) * DZ_N + z) * HW_N + pp0 + pl;
    outp[gidx] = F3[gidx] + sOut[pl][cch];
  }
}

// ---------------------------------------------------------------------------
extern "C" void kernel_launch(void* const* d_in, const int* in_sizes, int n_in,
                              void* d_out, int out_size, void* d_ws, size_t ws_size,
                              hipStream_t stream) {
  (void)in_sizes; (void)n_in; (void)out_size; (void)ws_size;
  const float* F3      = (const float*)d_in[0];
  const float* F2      = (const float*)d_in[1];
  const float* Wq      = (const float*)d_in[2];
  const float* Wk      = (const float*)d_in[3];
  const float* Wv      = (const float*)d_in[4];
  const float* Wp      = (const float*)d_in[5];
  const float* ln_q_g  = (const float*)d_in[6];
  const float* ln_q_b  = (const float*)d_in[7];
  const float* ln_kv_g = (const float*)d_in[8];
  const float* ln_kv_b = (const float*)d_in[9];
  const float* conv1_w = (const float*)d_in[10];
  const float* bn_g    = (const float*)d_in[11];
  const float* bn_b    = (const float*)d_in[12];
  const float* conv2_w = (const float*)d_in[13];
  const float* conv2_b = (const float*)d_in[14];
  const float* lam     = (const float*)d_in[15];
  const int*   D0      = (const int*)d_in[16];
  const int*   slab    = (const int*)d_in[17];
  float* out = (float*)d_out;

  char* ws = (char*)d_ws;
  size_t off = 0;
  auto alloc = [&](size_t bytes) {
    void* p = ws + off;
    off += (bytes + 255) & ~(size_t)255;
    return p;
  };
  const int QROWS = B_N * DZ_N * HW_N;   // 36864
  const int KVROWS = B_N * K_N * HW_N;   // 9216
  float* Qraw = (float*)alloc((size_t)QROWS * E_N * 4);   // -> reused as O
  float* Kraw = (float*)alloc((size_t)KVROWS * E_N * 4);  // Hp first
  float* Vraw = (float*)alloc((size_t)KVROWS * E_N * 4);
  ushort_t* Qbf = (ushort_t*)alloc((size_t)QROWS * E_N * 2);
  ushort_t* Kpk = (ushort_t*)alloc((size_t)KVROWS * E_N * 2);
  ushort_t* Vtp = (ushort_t*)alloc((size_t)KVROWS * E_N * 2);
  float* topo = (float*)alloc((size_t)B_N * K_N * HW_N * 4);
  float* part = (float*)alloc((size_t)64 * HW_N * 4);
  float* Hp = Kraw;                    // dead before proj_gemm K runs
  float* O  = Qraw;                    // Qraw dead after ln_bf16(Q)

  // 1) topo branch
  topo_conv1<<<256, 384, 0, stream>>>(F2, conv1_w, Hp);
  topo_mid<<<64, 576, 0, stream>>>(Hp, bn_g, bn_b, conv2_w, part);
  topo_final2<<<16, 576, 0, stream>>>(part, conv2_b, topo);
  // 2) projections (fp32); K/V col-split x2 for occupancy
  proj_gemm<128, 256><<<dim3(QROWS / 64, 1), 256, 0, stream>>>(
      F3, Wq, Qraw, DZ_N, C3_N * DZ_N * HW_N, HW_N, 1, DZ_N * HW_N);
  proj_gemm<96, 128><<<dim3(KVROWS / 64, 2), 256, 0, stream>>>(
      F2, Wk, Kraw, K_N, C2_N * HW_N * K_N, 1, K_N, HW_N * K_N);
  proj_gemm<96, 128><<<dim3(KVROWS / 64, 2), 256, 0, stream>>>(
      F2, Wv, Vraw, K_N, C2_N * HW_N * K_N, 1, K_N, HW_N * K_N);
  // 3) layernorm -> bf16 (K fused with swizzled packing; V fused in pack)
  ln_bf16<<<QROWS / 4, 256, 0, stream>>>(Qraw, ln_q_g, ln_q_b, Qbf);
  ln_k_pack<<<KVROWS / 4, 256, 0, stream>>>(Kraw, ln_kv_g, ln_kv_b, Kpk);
  pack_vt_ln<<<B_N * K_N * 9, 256, 0, stream>>>(Vraw, ln_kv_g, ln_kv_b, Vtp);
  // 4) attention (transposed dataflow, register-resident P)
  attn_kernel<<<1152, 256, 0, stream>>>(
      Qbf, Kpk, Vtp, topo, lam, D0, slab, O);
  // 5) output projection + residual
  out_proj<<<QROWS / 64, 256, 0, stream>>>(O, Wp, F3, out);
}

// Round 9
// 330.210 us; speedup vs baseline: 2.5268x; 1.1675x over previous
//
#include <hip/hip_runtime.h>

typedef float f32x4 __attribute__((ext_vector_type(4)));
typedef __bf16 bf16x8 __attribute__((ext_vector_type(8)));
typedef unsigned short ushort_t;

#define DEV_INLINE __device__ __forceinline__

constexpr int B_N  = 2;
constexpr int C3_N = 128;
constexpr int C2_N = 96;
constexpr int DZ_N = 32;
constexpr int H_N  = 24;
constexpr int W_N  = 24;
constexpr int K_N  = 8;
constexpr int E_N  = 256;
constexpr int HW_N = 576;

DEV_INLINE unsigned short f2bf(float x) {
  union { float f; unsigned u; } v; v.f = x;
  unsigned r = v.u + 0x7FFFu + ((v.u >> 16) & 1u);
  return (unsigned short)(r >> 16);
}

// ---------------------------------------------------------------------------
// Topo kernel A: partial 3x3 conv (C2->64), split over 4 c-chunks of 24.
// ---------------------------------------------------------------------------
__global__ __launch_bounds__(384) void topo_conv1(
    const float* __restrict__ F2, const float* __restrict__ W1,
    float* __restrict__ Hp) {
  const int bid = blockIdx.x;
  const int cc = bid & 3;
  const int tg = (bid >> 2) & 3;
  const int bk = bid >> 4;           // 0..15 = b*8 + k
  const int b = bk >> 3, k = bk & 7;
  const int tid = threadIdx.x;
  const int y = tid >> 4;            // 0..23
  const int tq = tid & 15;           // 0..15

  __shared__ float simg[8][26][28];
  __shared__ float sw[16 * 97];

  float acc[24];
#pragma unroll
  for (int i = 0; i < 24; i++) acc[i] = 0.f;

  float* simgf = &simg[0][0][0];
  for (int i = tid; i < 8 * 26 * 28; i += 384) simgf[i] = 0.f;
  __syncthreads();

  for (int ch = 0; ch < 3; ch++) {
    if (ch) __syncthreads();
    const int c0 = cc * 24 + ch * 8;
    for (int i = tid; i < 8 * 24 * 24; i += 384) {
      int c = i / 576, p = i - c * 576;
      int yy = p / 24, xx = p - yy * 24;
      simg[c][yy + 1][xx + 1] =
          F2[(((b * C2_N + c0 + c) * H_N + yy) * W_N + xx) * K_N + k];
    }
    for (int i = tid; i < 16 * 72; i += 384) {
      int t2 = i / 72, rest = i - t2 * 72;
      int c = rest / 9, q = rest - c * 9;
      sw[t2 * 97 + c * 12 + q] =
          W1[(tg * 16 + t2) * (C2_N * 9) + (c0 + c) * 9 + q];
    }
    __syncthreads();
#pragma unroll 1
    for (int c = 0; c < 8; c++) {
      float w[9];
#pragma unroll
      for (int q = 0; q < 9; q++) w[q] = sw[tq * 97 + c * 12 + q];
#pragma unroll
      for (int dy = 0; dy < 3; dy++) {
        float r[26];
#pragma unroll
        for (int xx = 0; xx < 26; xx++) r[xx] = simg[c][y + dy][xx];
#pragma unroll
        for (int dx = 0; dx < 3; dx++) {
          float wv = w[dy * 3 + dx];
#pragma unroll
          for (int xx = 0; xx < 24; xx++)
            acc[xx] = fmaf(wv, r[xx + dx], acc[xx]);
        }
      }
    }
  }
  const int t = tg * 16 + tq;
  float* dst = &Hp[((cc * 16 + bk) * 64 + t) * HW_N + y * 24];
#pragma unroll
  for (int xx = 0; xx < 24; xx++) dst[xx] = acc[xx];
}

// ---------------------------------------------------------------------------
// Topo B1: per-(bk, t-group) partial bn+relu+1x1 reduction. 64 blocks.
// ---------------------------------------------------------------------------
__global__ __launch_bounds__(576) void topo_mid(
    const float* __restrict__ Hp, const float* __restrict__ bn_g,
    const float* __restrict__ bn_b, const float* __restrict__ W2,
    float* __restrict__ part) {
  const int bid = blockIdx.x;
  const int tg = bid & 3, bk = bid >> 2;
  const int p = threadIdx.x;
  const float inv = rsqrtf(1.0f + 1e-5f);
  float acc = 0.f;
#pragma unroll 1
  for (int tt = 0; tt < 16; tt++) {
    const int t = tg * 16 + tt;
    float v = 0.f;
#pragma unroll
    for (int c4 = 0; c4 < 4; c4++)
      v += Hp[((c4 * 16 + bk) * 64 + t) * HW_N + p];
    acc = fmaf(W2[t], fmaxf(fmaf(bn_g[t] * inv, v, bn_b[t]), 0.f), acc);
  }
  part[(bk * 4 + tg) * HW_N + p] = acc;
}

// ---------------------------------------------------------------------------
// Topo B2: combine partials + neighbor halo sum. 16 blocks.
// ---------------------------------------------------------------------------
__global__ __launch_bounds__(576) void topo_final2(
    const float* __restrict__ part, const float* __restrict__ b2,
    float* __restrict__ topo) {
  const int bk = blockIdx.x;
  const int p = threadIdx.x;
  __shared__ float pp[26][28];
  float* ppf = &pp[0][0];
  for (int i = p; i < 26 * 28; i += 576) ppf[i] = 0.f;
  float acc = b2[0];
#pragma unroll
  for (int tg = 0; tg < 4; tg++) acc += part[(bk * 4 + tg) * HW_N + p];
  __syncthreads();
  pp[p / 24 + 1][p % 24 + 1] = acc;
  __syncthreads();
  const int yy = p / 24 + 1, xx = p % 24 + 1;
  float s = pp[yy-1][xx-1] + pp[yy-1][xx] + pp[yy-1][xx+1]
          + pp[yy][xx-1]                  + pp[yy][xx+1]
          + pp[yy+1][xx-1] + pp[yy+1][xx] + pp[yy+1][xx+1];
  topo[bk * HW_N + p] = acc + 0.5f * s;
}

// ---------------------------------------------------------------------------
// pack_all: W matrices -> bf16 [n][k] row-major (MFMA B/A-frag friendly).
// grid 896: [0,256) Wq n; [256,512) Wk n; [512,768) Wv n; [768,896) Wp c.
// ---------------------------------------------------------------------------
__global__ __launch_bounds__(256) void pack_all(
    const float* __restrict__ Wq, const float* __restrict__ Wk,
    const float* __restrict__ Wv, const float* __restrict__ Wp,
    ushort_t* __restrict__ Wqp, ushort_t* __restrict__ Wkp,
    ushort_t* __restrict__ Wvp, ushort_t* __restrict__ Wpp) {
  const int bblk = blockIdx.x, t = threadIdx.x;
  if (bblk < 256) {
    if (t < 128) Wqp[bblk * 128 + t] = f2bf(Wq[t * 256 + bblk]);
  } else if (bblk < 512) {
    const int n = bblk - 256;
    if (t < 96) Wkp[n * 96 + t] = f2bf(Wk[t * 256 + n]);
  } else if (bblk < 768) {
    const int n = bblk - 512;
    if (t < 96) Wvp[n * 96 + t] = f2bf(Wv[t * 256 + n]);
  } else {
    const int c = bblk - 768;
    Wpp[c * 256 + t] = f2bf(Wp[t * 128 + c]);
  }
}

// ---------------------------------------------------------------------------
// Transposed MFMA projection: out = X @ W for 64 rows x 256 cols per block.
// A-operand = packed W^T rows (global b128), B-operand = X rows staged in
// LDS (bf16, rotation-swizzled groups). Lane holds full out row m=col ->
// MODE 0: fp32 row-major (f32x4); MODE 1: fused LN -> bf16 row-major;
// MODE 2: fused LN -> packed swizzled Kpk chunks.
// ---------------------------------------------------------------------------
template <int CIN, int MODE>
__global__ __launch_bounds__(256) void proj_mfma(
    const float* __restrict__ src, const ushort_t* __restrict__ Wpk,
    void* __restrict__ outp, const float* __restrict__ g,
    const float* __restrict__ bb,
    int outer, int bStride, int oStride, int pStride, int cStride) {
  __shared__ ushort_t sA[64 * 128];   // 16 KB, group-rotated by row
  __shared__ int sRB[64];
  const int tid = threadIdx.x;
  const int rowG = blockIdx.x * 64;
  if (tid < 64) {
    int rr = rowG + tid;
    int b2 = rr / (outer * HW_N);
    int rem = rr - b2 * outer * HW_N;
    int o = rem / HW_N;
    int p = rem - o * HW_N;
    sRB[tid] = b2 * bStride + o * oStride + p * pStride;
  }
  __syncthreads();
  {
    const int r = tid & 63, kg = tid >> 6;
    constexpr int KC = CIN / 4;
    const float* s0 = src + sRB[r];
#pragma unroll
    for (int i = 0; i < KC; i += 2) {
      const int k = kg * KC + i;
      const float x0 = s0[k * cStride];
      const float x1 = s0[(k + 1) * cStride];
      const unsigned pr = (unsigned)f2bf(x0) | ((unsigned)f2bf(x1) << 16);
      ((unsigned*)sA)[r * 64 + (((k >> 3) + r) & 15) * 4 + ((k & 7) >> 1)] = pr;
    }
  }
  __syncthreads();
  const int wv = tid >> 6, lane = tid & 63;
  const int quad = lane >> 4, col = lane & 15;
  const int m = wv * 16 + col;
  constexpr int KS = CIN / 32;
  bf16x8 xb[KS];
#pragma unroll
  for (int ks = 0; ks < KS; ks++)
    xb[ks] = *(const bf16x8*)&sA[m * 128 + (((ks * 4 + quad) + m) & 15) * 8];
  f32x4 acc[16];
#pragma unroll
  for (int nt = 0; nt < 16; nt++) {
    const ushort_t* wrow = Wpk + (nt * 16 + col) * CIN + quad * 8;
    f32x4 a = (f32x4){0.f, 0.f, 0.f, 0.f};
#pragma unroll
    for (int ks = 0; ks < KS; ks++) {
      bf16x8 wf = *(const bf16x8*)&wrow[ks * 32];
      a = __builtin_amdgcn_mfma_f32_16x16x32_bf16(wf, xb[ks], a, 0, 0, 0);
    }
    acc[nt] = a;
  }
  const int mrow = rowG + m;
  if (MODE == 0) {
    float* dst = (float*)outp + (size_t)mrow * E_N;
#pragma unroll
    for (int nt = 0; nt < 16; nt++)
      *(f32x4*)&dst[nt * 16 + quad * 4] = acc[nt];
  } else {
    float s = 0.f;
#pragma unroll
    for (int nt = 0; nt < 16; nt++)
      s += acc[nt][0] + acc[nt][1] + acc[nt][2] + acc[nt][3];
    s += __shfl_xor(s, 16); s += __shfl_xor(s, 32);
    const float mean = s * (1.f / 256.f);
    float v = 0.f;
#pragma unroll
    for (int nt = 0; nt < 16; nt++)
#pragma unroll
      for (int r = 0; r < 4; r++) {
        const float d = acc[nt][r] - mean;
        v += d * d;
      }
    v += __shfl_xor(v, 16); v += __shfl_xor(v, 32);
    const float rstd = rsqrtf(v * (1.f / 256.f) + 1e-5f);
    if (MODE == 1) {
      ushort_t* dst = (ushort_t*)outp + (size_t)mrow * E_N;
#pragma unroll
      for (int nt = 0; nt < 16; nt++) {
        const int n0 = nt * 16 + quad * 4;
        const float4 gv = *(const float4*)&g[n0];
        const float4 bv = *(const float4*)&bb[n0];
        ushort4 o;
        o.x = f2bf(fmaf((acc[nt][0] - mean) * rstd, gv.x, bv.x));
        o.y = f2bf(fmaf((acc[nt][1] - mean) * rstd, gv.y, bv.y));
        o.z = f2bf(fmaf((acc[nt][2] - mean) * rstd, gv.z, bv.z));
        o.w = f2bf(fmaf((acc[nt][3] - mean) * rstd, gv.w, bv.w));
        *(ushort4*)&dst[n0] = o;
      }
    } else {  // MODE 2: packed swizzled Kpk chunks
      const int bk = mrow / HW_N;
      const int p = mrow - bk * HW_N;
      const int pc = p >> 6, mm = p & 63;
#pragma unroll
      for (int nt = 0; nt < 16; nt++) {
        const int n0 = nt * 16 + quad * 4;
        const float4 gv = *(const float4*)&g[n0];
        const float4 bv = *(const float4*)&bb[n0];
        ushort4 o;
        o.x = f2bf(fmaf((acc[nt][0] - mean) * rstd, gv.x, bv.x));
        o.y = f2bf(fmaf((acc[nt][1] - mean) * rstd, gv.y, bv.y));
        o.z = f2bf(fmaf((acc[nt][2] - mean) * rstd, gv.z, bv.z));
        o.w = f2bf(fmaf((acc[nt][3] - mean) * rstd, gv.w, bv.w));
        const int h = nt >> 2;
        const int grp = ((nt & 3) * 2 + (quad >> 1)) ^ (mm & 7);
        ushort_t* dst = (ushort_t*)outp +
            ((size_t)((bk * 4 + h) * 9 + pc)) * 4096 +
            mm * 64 + grp * 8 + (quad & 1) * 4;
        *(ushort4*)dst = o;
      }
    }
  }
}

// ---------------------------------------------------------------------------
// pack_vt_ln: fused LayerNorm(V) + transpose-pack (unchanged from R8).
// ---------------------------------------------------------------------------
__global__ __launch_bounds__(256) void pack_vt_ln(
    const float* __restrict__ Vraw, const float* __restrict__ g,
    const float* __restrict__ bb, ushort_t* __restrict__ Vtp) {
  const int bid = blockIdx.x;
  const int pc = bid % 9;
  const int bk = bid / 9;
  const int tid = threadIdx.x;
  __shared__ ushort_t sT[64][264];
  {
    const int m = tid >> 2, jj = tid & 3;
    const int row = bk * HW_N + pc * 64 + m;
    const float* src = &Vraw[(size_t)row * E_N + jj * 64];
    float4 xv[16];
    float s = 0.f;
#pragma unroll
    for (int i = 0; i < 16; i++) {
      xv[i] = *(const float4*)&src[i * 4];
      s += xv[i].x + xv[i].y + xv[i].z + xv[i].w;
    }
    s += __shfl_xor(s, 1); s += __shfl_xor(s, 2);
    const float mean = s * (1.f / 256.f);
    float v = 0.f;
#pragma unroll
    for (int i = 0; i < 16; i++) {
      xv[i].x -= mean; xv[i].y -= mean; xv[i].z -= mean; xv[i].w -= mean;
      v += xv[i].x * xv[i].x + xv[i].y * xv[i].y +
           xv[i].z * xv[i].z + xv[i].w * xv[i].w;
    }
    v += __shfl_xor(v, 1); v += __shfl_xor(v, 2);
    const float rstd = rsqrtf(v * (1.f / 256.f) + 1e-5f);
    ushort_t* drow = &sT[m][jj * 64];
#pragma unroll
    for (int i = 0; i < 16; i++) {
      const float4 gv = *(const float4*)&g[jj * 64 + i * 4];
      const float4 bv = *(const float4*)&bb[jj * 64 + i * 4];
      ushort4 o;
      o.x = f2bf(fmaf(xv[i].x * rstd, gv.x, bv.x));
      o.y = f2bf(fmaf(xv[i].y * rstd, gv.y, bv.y));
      o.z = f2bf(fmaf(xv[i].z * rstd, gv.z, bv.z));
      o.w = f2bf(fmaf(xv[i].w * rstd, gv.w, bv.w));
      *(ushort4*)&drow[i * 4] = o;
    }
  }
  __syncthreads();
  const int hh = tid >> 6, d = tid & 63;
  __attribute__((aligned(16))) ushort_t tmp[64];
#pragma unroll
  for (int k = 0; k < 64; k++) {
    const int pk = (k & 32) + ((k & 4) << 2) + ((k & 24) >> 1) + (k & 3);
    tmp[k] = sT[pk][hh * 64 + d];
  }
  const int chunk = (bk * 4 + hh) * 9 + pc;
  uint4* dst = (uint4*)&Vtp[chunk * 4096 + d * 64];
  const int sw = d & 7;
#pragma unroll
  for (int gg = 0; gg < 8; gg++) dst[gg ^ sw] = ((const uint4*)tmp)[gg];
}

// ---------------------------------------------------------------------------
// Flash-style slab cross attention v9 (= v8 + bf16 O output).
// ---------------------------------------------------------------------------
__global__ __launch_bounds__(256) void attn_kernel(
    const ushort_t* __restrict__ Qbf, const ushort_t* __restrict__ Kpk,
    const ushort_t* __restrict__ Vtp, const float* __restrict__ topo,
    const float* __restrict__ lamp, const int* __restrict__ D0p,
    const int* __restrict__ slabp, ushort_t* __restrict__ Obf) {
  const int bid = blockIdx.x;
  const int hb = bid & 7;
  const int h = hb & 3, b = hb >> 2;
  const int zp = (bid >> 3) & 15;
  const int pb = bid >> 7;                 // 0..8
  const int p0 = pb * 64;
  const int tid = threadIdx.x;
  const int w = tid >> 6, lane = tid & 63;
  const int quad = lane >> 4, col = lane & 15;
  const int z = zp * 2 + (w >> 1);
  const int th = w & 1;

  const float LOG2E = 1.44269504f;
  const float lam2 = lamp[0] * LOG2E;
  const float S2 = 0.125f * LOG2E;
  const int D0 = D0p[0], slab = slabp[0];
  const float step = (float)(D0 - 1) / (float)(DZ_N - 1);

  int kkw, kka, kkb;
  {
    int z0 = (int)floorf(fmaf((float)z, step, 0.5f));
    int kv = z0 / slab;
    kkw = kv < 0 ? 0 : (kv > K_N - 1 ? K_N - 1 : kv);
    int z0a = (int)floorf(fmaf((float)(zp * 2), step, 0.5f));
    int z0b = (int)floorf(fmaf((float)(zp * 2 + 1), step, 0.5f));
    int ka = z0a / slab; ka = ka < 0 ? 0 : (ka > K_N - 1 ? K_N - 1 : ka);
    int kb = z0b / slab; kb = kb < 0 ? 0 : (kb > K_N - 1 ? K_N - 1 : kb);
    kka = ka < kb ? ka : kb;
    kkb = ka < kb ? kb : ka;
  }
  const int c_lo = (kka - 1) < 0 ? 0 : (kka - 1);
  const int c_hi = (kkb + 1) > (K_N - 1) ? (K_N - 1) : (kkb + 1);

  __shared__ ushort_t sKV[2][8192];    // dbuf: [buf][ K 8KB | V 8KB ] = 32 KB

  auto issue_fill = [&](int buf, int c, int pc) {
    const size_t cb = ((size_t)(((b * K_N + c) * 4 + h) * 9) + pc) * 4096;
#pragma unroll
    for (int j = 0; j < 4; j++) {
      const int seg = (w << 2) + j;    // 0..15
      const ushort_t* gsrc = (w < 2)
          ? (Kpk + cb + seg * 512 + lane * 8)
          : (Vtp + cb + (seg - 8) * 512 + lane * 8);
      ushort_t* ldst = &sKV[buf][seg * 512];
      __builtin_amdgcn_global_load_lds(
          (const __attribute__((address_space(1))) void*)gsrc,
          (__attribute__((address_space(3))) void*)ldst, 16, 0, 0);
    }
  };

  // Q B-frags (2 tiles)
  bf16x8 bq[2][2];
  const int qrow0 = (b * DZ_N + z) * HW_N + p0 + th * 32;
#pragma unroll
  for (int t = 0; t < 2; t++) {
    const ushort_t* qp = &Qbf[(qrow0 + t * 16 + col) * E_N + h * 64 + quad * 8];
    bq[t][0] = *(const bf16x8*)qp;
    bq[t][1] = *(const bf16x8*)(qp + 32);
  }

  f32x4 oacc[2][4];
#pragma unroll
  for (int t = 0; t < 2; t++)
#pragma unroll
    for (int dt = 0; dt < 4; dt++) oacc[t][dt] = (f32x4){0.f, 0.f, 0.f, 0.f};
  float lsum[2] = {0.f, 0.f};

  const int s7 = col & 7;
  const int o1 = (quad ^ s7) * 8;
  const int o2 = ((quad + 4) ^ s7) * 8;

  int buf = 0;
  issue_fill(0, c_lo, 0);   // prologue

  for (int c = c_lo; c <= c_hi; c++) {
    const bool act = (c >= kkw - 1) && (c <= kkw + 1);
    const float biasE2 = ((c == kkw) ? -20.0f : -20.5f) * LOG2E;
    const float* topoc = &topo[(b * K_N + c) * HW_N + p0];
#pragma unroll 1
    for (int pc = 0; pc < 9; pc++) {
      __syncthreads();   // drains in-flight fill; all waves arrive
      {
        int pc2 = pc + 1, c2 = c;
        if (pc2 == 9) { pc2 = 0; c2 = c + 1; }
        if (c2 <= c_hi) issue_fill(buf ^ 1, c2, pc2);
      }
      const ushort_t* sKb = &sKV[buf][0];
      const ushort_t* sVb = &sKV[buf][4096];
      buf ^= 1;
      if (!act) continue;

      bf16x8 ka[4][2];
#pragma unroll
      for (int kt = 0; kt < 4; kt++) {
        const ushort_t* kr = sKb + (kt * 16 + col) * 64;
        ka[kt][0] = *(const bf16x8*)(kr + o1);
        ka[kt][1] = *(const bf16x8*)(kr + o2);
      }

      bf16x8 pfrag[2][2];
#pragma unroll
      for (int t = 0; t < 2; t++) {
        f32x4 sv[4];
#pragma unroll
        for (int kt = 0; kt < 4; kt++) {
          f32x4 acc = (f32x4){0.f, 0.f, 0.f, 0.f};
          acc = __builtin_amdgcn_mfma_f32_16x16x32_bf16(ka[kt][0], bq[t][0], acc, 0, 0, 0);
          acc = __builtin_amdgcn_mfma_f32_16x16x32_bf16(ka[kt][1], bq[t][1], acc, 0, 0, 0);
          sv[kt] = acc;
        }
        float xv[4][4];
#pragma unroll
        for (int kt = 0; kt < 4; kt++)
#pragma unroll
          for (int r = 0; r < 4; r++)
            xv[kt][r] = fmaf(sv[kt][r], S2, biasE2);
        if (pc == pb) {
          const int ctt = th * 2 + t;
          const float tv2 = lam2 * topoc[th * 32 + t * 16 + col];
          const bool qok = ((col >> 2) == quad);
#pragma unroll
          for (int kt = 0; kt < 4; kt++)
#pragma unroll
            for (int r = 0; r < 4; r++)
              xv[kt][r] += (qok && kt == ctt && (col & 3) == r) ? tv2 : 0.f;
        }
        float ev[4][4];
        float ls = 0.f;
#pragma unroll
        for (int kt = 0; kt < 4; kt++)
#pragma unroll
          for (int r = 0; r < 4; r++) {
            ev[kt][r] = __builtin_amdgcn_exp2f(xv[kt][r]);
            ls += ev[kt][r];
          }
        lsum[t] += ls;
#pragma unroll
        for (int f = 0; f < 2; f++) {
          union { uint4 u; bf16x8 v; } pk;
          pk.u.x = __builtin_amdgcn_perm(__float_as_uint(ev[f*2][1]),
                                         __float_as_uint(ev[f*2][0]), 0x07060302u);
          pk.u.y = __builtin_amdgcn_perm(__float_as_uint(ev[f*2][3]),
                                         __float_as_uint(ev[f*2][2]), 0x07060302u);
          pk.u.z = __builtin_amdgcn_perm(__float_as_uint(ev[f*2+1][1]),
                                         __float_as_uint(ev[f*2+1][0]), 0x07060302u);
          pk.u.w = __builtin_amdgcn_perm(__float_as_uint(ev[f*2+1][3]),
                                         __float_as_uint(ev[f*2+1][2]), 0x07060302u);
          pfrag[t][f] = pk.v;
        }
      }

#pragma unroll
      for (int dt = 0; dt < 4; dt++) {
        const ushort_t* vr = sVb + (dt * 16 + col) * 64;
        bf16x8 va0 = *(const bf16x8*)(vr + o1);
        bf16x8 va1 = *(const bf16x8*)(vr + o2);
#pragma unroll
        for (int t = 0; t < 2; t++) {
          oacc[t][dt] = __builtin_amdgcn_mfma_f32_16x16x32_bf16(va0, pfrag[t][0], oacc[t][dt], 0, 0, 0);
          oacc[t][dt] = __builtin_amdgcn_mfma_f32_16x16x32_bf16(va1, pfrag[t][1], oacc[t][dt], 0, 0, 0);
        }
      }
    }
  }

  // epilogue: l-reduce over quads, write bf16 O
#pragma unroll
  for (int t = 0; t < 2; t++) {
    float l = lsum[t];
    l += __shfl_xor(l, 16);
    l += __shfl_xor(l, 32);
    const float invl = 1.f / l;
    const int row = qrow0 + t * 16 + col;
    ushort_t* orow = &Obf[(size_t)row * E_N + h * 64];
#pragma unroll
    for (int dt = 0; dt < 4; dt++) {
      ushort4 o;
      o.x = f2bf(oacc[t][dt][0] * invl);
      o.y = f2bf(oacc[t][dt][1] * invl);
      o.z = f2bf(oacc[t][dt][2] * invl);
      o.w = f2bf(oacc[t][dt][3] * invl);
      *(ushort4*)&orow[dt * 16 + quad * 4] = o;
    }
  }
}

// ---------------------------------------------------------------------------
// Output projection (MFMA) + residual. A = Obf rows (global b128 frags),
// B = packed Wp^T rows. LDS transpose epilogue for coalesced c-major writes.
// ---------------------------------------------------------------------------
__global__ __launch_bounds__(256) void out_proj_mfma(
    const ushort_t* __restrict__ Obf, const ushort_t* __restrict__ Wpp,
    const float* __restrict__ F3, float* __restrict__ outp) {
  __shared__ float sOut[64][129];
  const int tid = threadIdx.x;
  const int rowG = blockIdx.x * 64;
  const int wv = tid >> 6, lane = tid & 63;
  const int quad = lane >> 4, col = lane & 15;

  const ushort_t* xrow = &Obf[(size_t)(rowG + wv * 16 + col) * E_N + quad * 8];
  bf16x8 af[8];
#pragma unroll
  for (int ks = 0; ks < 8; ks++) af[ks] = *(const bf16x8*)&xrow[ks * 32];

#pragma unroll
  for (int nt = 0; nt < 8; nt++) {
    const ushort_t* wrow = &Wpp[(nt * 16 + col) * 256 + quad * 8];
    f32x4 a = (f32x4){0.f, 0.f, 0.f, 0.f};
#pragma unroll
    for (int ks = 0; ks < 8; ks++) {
      bf16x8 wf = *(const bf16x8*)&wrow[ks * 32];
      a = __builtin_amdgcn_mfma_f32_16x16x32_bf16(af[ks], wf, a, 0, 0, 0);
    }
#pragma unroll
    for (int r = 0; r < 4; r++)
      sOut[wv * 16 + quad * 4 + r][nt * 16 + col] = a[r];
  }
  __syncthreads();
  const int b = rowG / (DZ_N * HW_N);
  const int rem = rowG - b * DZ_N * HW_N;
  const int z = rem / HW_N;
  const int pp0 = rem - z * HW_N;
  const int pl = tid & 63, cg = tid >> 6;
  for (int c = cg * 32; c < cg * 32 + 32; c++) {
    const int gidx = ((b * C3_N + c) * DZ_N + z) * HW_N + pp0 + pl;
    outp[gidx] = F3[gidx] + sOut[pl][c];
  }
}

// ---------------------------------------------------------------------------
extern "C" void kernel_launch(void* const* d_in, const int* in_sizes, int n_in,
                              void* d_out, int out_size, void* d_ws, size_t ws_size,
                              hipStream_t stream) {
  (void)in_sizes; (void)n_in; (void)out_size; (void)ws_size;
  const float* F3      = (const float*)d_in[0];
  const float* F2      = (const float*)d_in[1];
  const float* Wq      = (const float*)d_in[2];
  const float* Wk      = (const float*)d_in[3];
  const float* Wv      = (const float*)d_in[4];
  const float* Wp      = (const float*)d_in[5];
  const float* ln_q_g  = (const float*)d_in[6];
  const float* ln_q_b  = (const float*)d_in[7];
  const float* ln_kv_g = (const float*)d_in[8];
  const float* ln_kv_b = (const float*)d_in[9];
  const float* conv1_w = (const float*)d_in[10];
  const float* bn_g    = (const float*)d_in[11];
  const float* bn_b    = (const float*)d_in[12];
  const float* conv2_w = (const float*)d_in[13];
  const float* conv2_b = (const float*)d_in[14];
  const float* lam     = (const float*)d_in[15];
  const int*   D0      = (const int*)d_in[16];
  const int*   slab    = (const int*)d_in[17];
  float* out = (float*)d_out;

  char* ws = (char*)d_ws;
  size_t off = 0;
  auto alloc = [&](size_t bytes) {
    void* p = ws + off;
    off += (bytes + 255) & ~(size_t)255;
    return p;
  };
  const int QROWS = B_N * DZ_N * HW_N;   // 36864
  const int KVROWS = B_N * K_N * HW_N;   // 9216
  ushort_t* Qbf = (ushort_t*)alloc((size_t)QROWS * E_N * 2);
  ushort_t* Kpk = (ushort_t*)alloc((size_t)KVROWS * E_N * 2);
  ushort_t* Vtp = (ushort_t*)alloc((size_t)KVROWS * E_N * 2);
  float* Vraw = (float*)alloc((size_t)KVROWS * E_N * 4);
  ushort_t* Obf = (ushort_t*)alloc((size_t)QROWS * E_N * 2);  // aliases Hp
  float* topo = (float*)alloc((size_t)B_N * K_N * HW_N * 4);
  float* part = (float*)alloc((size_t)64 * HW_N * 4);
  ushort_t* Wqp = (ushort_t*)alloc(256 * 128 * 2);
  ushort_t* Wkp = (ushort_t*)alloc(256 * 96 * 2);
  ushort_t* Wvp = (ushort_t*)alloc(256 * 96 * 2);
  ushort_t* Wpp = (ushort_t*)alloc(128 * 256 * 2);
  float* Hp = (float*)Obf;   // 9.4 MB <= Obf 18.9 MB; dead before attn

  // 1) weight packing + topo branch
  pack_all<<<896, 256, 0, stream>>>(Wq, Wk, Wv, Wp, Wqp, Wkp, Wvp, Wpp);
  topo_conv1<<<256, 384, 0, stream>>>(F2, conv1_w, Hp);
  topo_mid<<<64, 576, 0, stream>>>(Hp, bn_g, bn_b, conv2_w, part);
  topo_final2<<<16, 576, 0, stream>>>(part, conv2_b, topo);
  // 2) MFMA projections with fused LN/packing
  proj_mfma<128, 1><<<QROWS / 64, 256, 0, stream>>>(
      F3, Wqp, Qbf, ln_q_g, ln_q_b,
      DZ_N, C3_N * DZ_N * HW_N, HW_N, 1, DZ_N * HW_N);
  proj_mfma<96, 2><<<KVROWS / 64, 256, 0, stream>>>(
      F2, Wkp, Kpk, ln_kv_g, ln_kv_b,
      K_N, C2_N * HW_N * K_N, 1, K_N, HW_N * K_N);
  proj_mfma<96, 0><<<KVROWS / 64, 256, 0, stream>>>(
      F2, Wvp, Vraw, nullptr, nullptr,
      K_N, C2_N * HW_N * K_N, 1, K_N, HW_N * K_N);
  // 3) V: LN + transpose-pack
  pack_vt_ln<<<B_N * K_N * 9, 256, 0, stream>>>(Vraw, ln_kv_g, ln_kv_b, Vtp);
  // 4) attention -> bf16 O
  attn_kernel<<<1152, 256, 0, stream>>>(
      Qbf, Kpk, Vtp, topo, lam, D0, slab, Obf);
  // 5) output projection (MFMA) + residual
  out_proj_mfma<<<QROWS / 64, 256, 0, stream>>>(Obf, Wpp, F3, out);
}